// Round 3
// baseline (337.854 us; speedup 1.0000x reference)
//
#include <hip/hip_runtime.h>
#include <hip/hip_bf16.h>
#include <stdint.h>

#define Dd 64
#define Hh 8
#define Bb 4
#define Tt 2048
#define NT (Bb * Tt)   // 8192 token rows

typedef __attribute__((ext_vector_type(4))) float f32x4;
typedef __attribute__((ext_vector_type(2))) float f32x2;
typedef __attribute__((ext_vector_type(8))) __bf16 bf16x8;
typedef __attribute__((ext_vector_type(8))) uint16_t u16x8;
typedef __attribute__((ext_vector_type(4))) uint16_t u16x4;

// fp32 -> bf16 round-to-nearest-even (bit-level, storage as uint16)
__device__ __forceinline__ uint16_t f2bf(float f) {
    union { float f; uint32_t u; } v; v.f = f;
    return (uint16_t)((v.u + 0x7fffu + ((v.u >> 16) & 1u)) >> 16);
}

// -------------------- K1: per-head QKV projections (fp32 -> bf16) ----------
// grid (128 row-tiles, H, 3 mats), block 256.  out[h][row][e] bf16.
__global__ __launch_bounds__(256) void qkv_kernel(
    const float* __restrict__ x,
    const float* __restrict__ Wq, const float* __restrict__ bq,
    const float* __restrict__ Wk, const float* __restrict__ bk,
    const float* __restrict__ Wv, const float* __restrict__ bv,
    uint16_t* __restrict__ qb, uint16_t* __restrict__ kb, uint16_t* __restrict__ vb)
{
    __shared__ float xs[64][68];
    __shared__ float ws[64][68];
    const int rt = blockIdx.x, h = blockIdx.y, m = blockIdx.z;
    const float* W    = (m == 0) ? Wq : (m == 1) ? Wk : Wv;
    const float* bias = (m == 0) ? bq : (m == 1) ? bk : bv;
    uint16_t*    out  = (m == 0) ? qb : (m == 1) ? kb : vb;
    const int t = threadIdx.x;
#pragma unroll
    for (int p = 0; p < 4; ++p) {
        int idx = p * 256 + t;
        int r = idx >> 4, c4 = (idx & 15) * 4;
        *(f32x4*)&xs[r][c4] = *(const f32x4*)&x[(size_t)(rt * 64 + r) * 64 + c4];
        *(f32x4*)&ws[r][c4] = *(const f32x4*)&W[(size_t)(h * 64 + r) * 64 + c4];
    }
    __syncthreads();
    const int lane = t & 63, wave = t >> 6;
    const int c0 = (lane & 15) * 4;
    const int r0 = (lane >> 4) + 4 * wave;   // 0..15
    float acc[4][4] = {};
#pragma unroll 8
    for (int k = 0; k < 64; ++k) {
        f32x4 wv = *(f32x4*)&ws[k][c0];
#pragma unroll
        for (int i = 0; i < 4; ++i) {
            float xv = xs[r0 + 16 * i][k];
            acc[i][0] += xv * wv[0]; acc[i][1] += xv * wv[1];
            acc[i][2] += xv * wv[2]; acc[i][3] += xv * wv[3];
        }
    }
    f32x4 bb = *(const f32x4*)&bias[h * 64 + c0];
#pragma unroll
    for (int i = 0; i < 4; ++i) {
        int row = rt * 64 + r0 + 16 * i;
        u16x4 o;
#pragma unroll
        for (int j = 0; j < 4; ++j) o[j] = f2bf(acc[i][j] + bb[j]);
        *(u16x4*)&out[((size_t)h * NT + row) * 64 + c0] = o;
    }
}

// -------------------- K2: causal flash attention (bf16 MFMA) ---------------
// grid (32 q-tiles, H, B), block 256 (4 waves). Wave owns 16 q-rows.
// Writes fp32 into concat layout cat[b][t][h*64+d].
__global__ __launch_bounds__(256) void attn_kernel(
    const uint16_t* __restrict__ qb, const uint16_t* __restrict__ kb,
    const uint16_t* __restrict__ vb, float* __restrict__ cat)
{
    __shared__ uint16_t Ks[64][72];      // K tile, row-major [key][d], +pad
    __shared__ uint16_t Vt[64][72];      // V tile transposed [d][key], +pad
    __shared__ uint16_t Ps[4][16][72];   // per-wave P stage [q][key], +pad
    const int qt = (int)gridDim.x - 1 - (int)blockIdx.x;  // big tiles first
    const int h = blockIdx.y, b = blockIdx.z;
    const int t = threadIdx.x, lane = t & 63, wave = t >> 6;
    const int l15 = lane & 15, g = lane >> 4;
    const size_t base = ((size_t)h * NT + (size_t)b * Tt) * 64;
    const uint16_t* Qh = qb + base;
    const uint16_t* Kh = kb + base;
    const uint16_t* Vh = vb + base;

    // Q fragments: A-layout row = lane&15, k = (lane>>4)*8 + e (contiguous 8)
    bf16x8 aq[2];
    {
        int qrow = qt * 64 + wave * 16 + l15;
        aq[0] = *(const bf16x8*)&Qh[(size_t)qrow * 64 + g * 8];
        aq[1] = *(const bf16x8*)&Qh[(size_t)qrow * 64 + 32 + g * 8];
    }
    f32x4 o[4] = {};              // O accum: [dt] x 4 rows
    float m_run[4], l_run[4];
#pragma unroll
    for (int r = 0; r < 4; ++r) { m_run[r] = -INFINITY; l_run[r] = 0.f; }

    const int nkv = qt + 1;
    for (int kv = 0; kv < nkv; ++kv) {
        __syncthreads();   // protect LDS reuse
        // stage K (row-major) and V (transposed)
#pragma unroll
        for (int p = 0; p < 2; ++p) {
            int idx = p * 256 + t;
            int r = idx >> 3, ch = (idx & 7) * 8;
            *(u16x8*)&Ks[r][ch] = *(const u16x8*)&Kh[(size_t)(kv * 64 + r) * 64 + ch];
            u16x8 vv = *(const u16x8*)&Vh[(size_t)(kv * 64 + r) * 64 + ch];
#pragma unroll
            for (int j = 0; j < 8; ++j) Vt[ch + j][r] = vv[j];
        }
        __syncthreads();

        // S = Q K^T for 4 key sub-tiles of 16
        f32x4 s[4];
#pragma unroll
        for (int kt = 0; kt < 4; ++kt) {
            bf16x8 bk0 = *(const bf16x8*)&Ks[kt * 16 + l15][g * 8];
            bf16x8 bk1 = *(const bf16x8*)&Ks[kt * 16 + l15][32 + g * 8];
            f32x4 z = {};
            z = __builtin_amdgcn_mfma_f32_16x16x32_bf16(aq[0], bk0, z, 0, 0, 0);
            z = __builtin_amdgcn_mfma_f32_16x16x32_bf16(aq[1], bk1, z, 0, 0, 0);
            s[kt] = z;
        }
        // causal mask only on the diagonal tile (kv == qt)
        if (kv == nkv - 1) {
#pragma unroll
            for (int kt = 0; kt < 4; ++kt) {
                int key = kt * 16 + l15;
#pragma unroll
                for (int r = 0; r < 4; ++r) {
                    int qr = wave * 16 + g * 4 + r;
                    if (key > qr) s[kt][r] = -INFINITY;
                }
            }
        }
        // online softmax (row r lives in 16 lanes sharing lane>>4)
        float mt[4];
#pragma unroll
        for (int r = 0; r < 4; ++r) {
            mt[r] = fmaxf(fmaxf(s[0][r], s[1][r]), fmaxf(s[2][r], s[3][r]));
            mt[r] = fmaxf(mt[r], __shfl_xor(mt[r], 1));
            mt[r] = fmaxf(mt[r], __shfl_xor(mt[r], 2));
            mt[r] = fmaxf(mt[r], __shfl_xor(mt[r], 4));
            mt[r] = fmaxf(mt[r], __shfl_xor(mt[r], 8));
        }
        float ls[4];
#pragma unroll
        for (int r = 0; r < 4; ++r) {
            float mnew = fmaxf(m_run[r], mt[r]);
            float alpha = __expf(m_run[r] - mnew);
            m_run[r] = mnew;
            l_run[r] *= alpha;
            o[0][r] *= alpha; o[1][r] *= alpha; o[2][r] *= alpha; o[3][r] *= alpha;
            float sum = 0.f;
#pragma unroll
            for (int kt = 0; kt < 4; ++kt) {
                float p = __expf(s[kt][r] - mnew);
                s[kt][r] = p;
                sum += p;
            }
            ls[r] = sum;
        }
#pragma unroll
        for (int r = 0; r < 4; ++r) {
            ls[r] += __shfl_xor(ls[r], 1);
            ls[r] += __shfl_xor(ls[r], 2);
            ls[r] += __shfl_xor(ls[r], 4);
            ls[r] += __shfl_xor(ls[r], 8);
            l_run[r] += ls[r];
        }
        // P (bf16) -> wave-private LDS, then read back as A-fragments
#pragma unroll
        for (int kt = 0; kt < 4; ++kt)
#pragma unroll
            for (int r = 0; r < 4; ++r)
                Ps[wave][g * 4 + r][kt * 16 + l15] = f2bf(s[kt][r]);
        // O += P V
#pragma unroll
        for (int c = 0; c < 2; ++c) {
            bf16x8 ap = *(const bf16x8*)&Ps[wave][l15][c * 32 + g * 8];
#pragma unroll
            for (int dt = 0; dt < 4; ++dt) {
                bf16x8 bv = *(const bf16x8*)&Vt[dt * 16 + l15][c * 32 + g * 8];
                o[dt] = __builtin_amdgcn_mfma_f32_16x16x32_bf16(ap, bv, o[dt], 0, 0, 0);
            }
        }
    }
    // epilogue: normalize and write to concat layout
    float inv[4];
#pragma unroll
    for (int r = 0; r < 4; ++r) inv[r] = 1.f / l_run[r];
#pragma unroll
    for (int dt = 0; dt < 4; ++dt)
#pragma unroll
        for (int r = 0; r < 4; ++r) {
            int row = qt * 64 + wave * 16 + g * 4 + r;
            cat[((size_t)b * Tt + row) * (Hh * 64) + h * 64 + dt * 16 + l15] =
                o[dt][r] * inv[r];
        }
}

// -------------------- K3: projection cat[8192x512] @ Wp[512x64] + bp -------
__global__ __launch_bounds__(256) void proj_kernel(
    const float* __restrict__ cat, const float* __restrict__ Wp,
    const float* __restrict__ bp, float* __restrict__ proj)
{
    __shared__ float cs[16][516];
    __shared__ float wps[128][64];
    const int rt = blockIdx.x;   // 512 blocks x 16 rows
    const int t = threadIdx.x;
#pragma unroll
    for (int p = 0; p < 8; ++p) {
        int idx = p * 256 + t;
        int r = idx >> 7, c4 = (idx & 127) * 4;
        *(f32x4*)&cs[r][c4] = *(const f32x4*)&cat[((size_t)rt * 16 + r) * 512 + c4];
    }
    const int c0 = (t & 31) * 2;
    const int r0 = t >> 5;          // 0..7
    float acc[2][2] = {};
    for (int kt = 0; kt < 4; ++kt) {
        __syncthreads();
#pragma unroll
        for (int p = 0; p < 8; ++p) {
            int idx = p * 256 + t;
            int r = idx >> 4, c4 = (idx & 15) * 4;
            *(f32x4*)&wps[r][c4] = *(const f32x4*)&Wp[(size_t)(kt * 128 + r) * 64 + c4];
        }
        __syncthreads();
#pragma unroll 4
        for (int k = 0; k < 128; ++k) {
            f32x2 w = *(f32x2*)&wps[k][c0];
            float a0 = cs[r0][kt * 128 + k];
            float a1 = cs[r0 + 8][kt * 128 + k];
            acc[0][0] += a0 * w[0]; acc[0][1] += a0 * w[1];
            acc[1][0] += a1 * w[0]; acc[1][1] += a1 * w[1];
        }
    }
    f32x2 bb = *(const f32x2*)&bp[c0];
#pragma unroll
    for (int i = 0; i < 2; ++i) {
        int row = rt * 16 + r0 + 8 * i;
        f32x2 ov = { acc[i][0] + bb[0], acc[i][1] + bb[1] };
        *(f32x2*)&proj[(size_t)row * 64 + c0] = ov;
    }
}

// -------------------- LayerNorm helper (wave = one row of 64) --------------
__device__ __forceinline__ float wave_ln(float s, float gamma, float beta) {
    float mu = s;
#pragma unroll
    for (int m = 1; m <= 32; m <<= 1) mu += __shfl_xor(mu, m);
    mu *= (1.f / 64.f);
    float d = s - mu;
    float v = d * d;
#pragma unroll
    for (int m = 1; m <= 32; m <<= 1) v += __shfl_xor(v, m);
    v *= (1.f / 64.f);
    return d * rsqrtf(v + 1e-5f) * gamma + beta;
}

// -------------------- K4: h1 = LN(x + proj) --------------------------------
__global__ __launch_bounds__(256) void ln1_kernel(
    const float* __restrict__ x, const float* __restrict__ proj,
    const float* __restrict__ g1, const float* __restrict__ be1,
    float* __restrict__ h1)
{
    const int t = threadIdx.x, lane = t & 63, wave = t >> 6;
    const size_t row = (size_t)blockIdx.x * 4 + wave;
    float s = x[row * 64 + lane] + proj[row * 64 + lane];
    h1[row * 64 + lane] = wave_ln(s, g1[lane], be1[lane]);
}

// -------------------- K5: FFN + residual + LN2 -> out ----------------------
// W1 (64KB) + W2 (64KB) fully LDS-resident. 512 blocks x 16 rows.
__global__ __launch_bounds__(256) void ffn_kernel(
    const float* __restrict__ h1,
    const float* __restrict__ W1, const float* __restrict__ b1,
    const float* __restrict__ W2, const float* __restrict__ b2,
    const float* __restrict__ g2, const float* __restrict__ be2,
    float* __restrict__ out)
{
    __shared__ float w1s[64 * 256];
    __shared__ float w2s[256 * 64];
    __shared__ float hs[16][68];
    __shared__ float hid[16][256];
    const int rt = blockIdx.x;
    const int t = threadIdx.x;
    // W1: 64*256 floats = 4096 f32x4; 4096/256 threads = 16 iterations.
    // (Round-0 bug: p<32 ran idx to 8191 -> OOB reads of W1/W2 and LDS smash
    //  of w2s/hs/hid. p<16 is exact.)
#pragma unroll
    for (int p = 0; p < 16; ++p) {
        int idx = p * 256 + t;
        ((f32x4*)w1s)[idx] = ((const f32x4*)W1)[idx];
        ((f32x4*)w2s)[idx] = ((const f32x4*)W2)[idx];
    }
    {
        int r = t >> 4, c4 = (t & 15) * 4;
        *(f32x4*)&hs[r][c4] = *(const f32x4*)&h1[((size_t)rt * 16 + r) * 64 + c4];
    }
    __syncthreads();
    // phase 1: hidden[r][t] = relu(h1[r] . W1[:,t] + b1[t])
    {
        float bias = b1[t];
        float acc[16];
#pragma unroll
        for (int r = 0; r < 16; ++r) acc[r] = bias;
#pragma unroll 4
        for (int k = 0; k < 64; ++k) {
            float w = w1s[k * 256 + t];
#pragma unroll
            for (int r = 0; r < 16; ++r) acc[r] += hs[r][k] * w;
        }
#pragma unroll
        for (int r = 0; r < 16; ++r) hid[r][t] = fmaxf(acc[r], 0.f);
    }
    __syncthreads();
    // phase 2: out[r][lane] = LN(h1[r][lane] + hidden[r] . W2[:,lane] + b2)
    const int lane = t & 63, wave = t >> 6;
    const float gg = g2[lane], be = be2[lane], bias2 = b2[lane];
#pragma unroll
    for (int i = 0; i < 4; ++i) {
        int r = wave + 4 * i;
        float a0 = bias2, a1 = 0.f, a2 = 0.f, a3 = 0.f;
#pragma unroll 2
        for (int k = 0; k < 256; k += 4) {
            a0 += hid[r][k]     * w2s[(k)     * 64 + lane];
            a1 += hid[r][k + 1] * w2s[(k + 1) * 64 + lane];
            a2 += hid[r][k + 2] * w2s[(k + 2) * 64 + lane];
            a3 += hid[r][k + 3] * w2s[(k + 3) * 64 + lane];
        }
        float s = (a0 + a1) + (a2 + a3) + hs[r][lane];
        out[((size_t)rt * 16 + r) * 64 + lane] = wave_ln(s, gg, be);
    }
}

// ---------------------------------------------------------------------------
extern "C" void kernel_launch(void* const* d_in, const int* in_sizes, int n_in,
                              void* d_out, int out_size, void* d_ws, size_t ws_size,
                              hipStream_t stream)
{
    (void)in_sizes; (void)n_in; (void)out_size; (void)ws_size;
    const float* x   = (const float*)d_in[0];
    const float* Wq  = (const float*)d_in[1];
    const float* bq  = (const float*)d_in[2];
    const float* Wk  = (const float*)d_in[3];
    const float* bk  = (const float*)d_in[4];
    const float* Wv  = (const float*)d_in[5];
    const float* bv  = (const float*)d_in[6];
    const float* Wp  = (const float*)d_in[7];
    const float* bp  = (const float*)d_in[8];
    const float* W1  = (const float*)d_in[9];
    const float* b1  = (const float*)d_in[10];
    const float* W2  = (const float*)d_in[11];
    const float* b2  = (const float*)d_in[12];
    const float* g1  = (const float*)d_in[13];
    const float* be1 = (const float*)d_in[14];
    const float* g2  = (const float*)d_in[15];
    const float* be2 = (const float*)d_in[16];
    float* outp = (float*)d_out;

    char* w = (char*)d_ws;
    uint16_t* qb = (uint16_t*)w;                       // [H][NT][64] bf16, 8MB
    uint16_t* kb = qb + (size_t)Hh * NT * 64;          // 8MB
    uint16_t* vb = kb + (size_t)Hh * NT * 64;          // 8MB
    float* cat   = (float*)(w + (size_t)3 * Hh * NT * 64 * 2);  // [NT][512] 16MB
    float* proj  = cat + (size_t)NT * 512;             // [NT][64] 2MB
    float* h1    = proj + (size_t)NT * 64;             // [NT][64] 2MB

    qkv_kernel<<<dim3(NT / 64, Hh, 3), dim3(256), 0, stream>>>(
        x, Wq, bq, Wk, bk, Wv, bv, qb, kb, vb);
    attn_kernel<<<dim3(Tt / 64, Hh, Bb), dim3(256), 0, stream>>>(qb, kb, vb, cat);
    proj_kernel<<<dim3(NT / 16), dim3(256), 0, stream>>>(cat, Wp, bp, proj);
    ln1_kernel<<<dim3(NT / 4), dim3(256), 0, stream>>>(x, proj, g1, be1, h1);
    ffn_kernel<<<dim3(NT / 16), dim3(256), 0, stream>>>(
        h1, W1, b1, W2, b2, g2, be2, outp);
}

// Round 4
// 240.992 us; speedup vs baseline: 1.4019x; 1.4019x over previous
//
#include <hip/hip_runtime.h>
#include <hip/hip_bf16.h>
#include <stdint.h>

#define Dd 64
#define Hh 8
#define Bb 4
#define Tt 2048
#define NT (Bb * Tt)   // 8192 token rows

typedef __attribute__((ext_vector_type(4))) float f32x4;
typedef __attribute__((ext_vector_type(2))) float f32x2;
typedef __attribute__((ext_vector_type(8))) __bf16 bf16x8;
typedef __attribute__((ext_vector_type(8))) uint16_t u16x8;
typedef __attribute__((ext_vector_type(4))) uint16_t u16x4;

// fp32 -> bf16 round-to-nearest-even (bit-level, storage as uint16)
__device__ __forceinline__ uint16_t f2bf(float f) {
    union { float f; uint32_t u; } v; v.f = f;
    return (uint16_t)((v.u + 0x7fffu + ((v.u >> 16) & 1u)) >> 16);
}

// XOR-swizzled LDS index for 64-row x 64-col u16 tiles, row stride 72.
// Element (row,k) lives at row*72 + (k ^ (((row>>3)&7)<<3)).
// Bijective within each aligned 8-chunk of k, so u16x8 (b128) accesses with
// the same XOR stay contiguous. Kills the 8-way bank conflicts of the
// transposed-V / transposed-W scalar staging writes (base bank 36*row ≡ same
// for row, row+8,... ; XOR spreads those lanes over distinct 16B slots).
#define SWZ(row, k) ((row) * 72 + ((k) ^ ((((row) >> 3) & 7) << 3)))
// P-stage tile: 16 q-rows; the colliding write lanes differ in q>>2.
#define PSZ(q, k)   ((q) * 72 + ((k) ^ ((((q) >> 2) & 3) << 3)))

// -------------------- K1: per-head QKV projections (bf16 MFMA) -------------
// grid (128 row-tiles, H, 3 mats), block 256 (4 waves).
// Wave w computes rows w*16..w*16+15 x all 64 cols via 8 mfma_16x16x32.
__global__ __launch_bounds__(256) void qkv_kernel(
    const float* __restrict__ x,
    const float* __restrict__ Wq, const float* __restrict__ bq,
    const float* __restrict__ Wk, const float* __restrict__ bk,
    const float* __restrict__ Wv, const float* __restrict__ bv,
    uint16_t* __restrict__ qb, uint16_t* __restrict__ kb, uint16_t* __restrict__ vb)
{
    __shared__ uint16_t WtF[64 * 72];   // W^T in bf16, swizzled: (e, k) -> W[k][e]
    const int rt = blockIdx.x, h = blockIdx.y, m = blockIdx.z;
    const float* W    = (m == 0) ? Wq : (m == 1) ? Wk : Wv;
    const float* bias = (m == 0) ? bq : (m == 1) ? bk : bv;
    uint16_t*    out  = (m == 0) ? qb : (m == 1) ? kb : vb;
    const int t = threadIdx.x, lane = t & 63, w = t >> 6;
    const int l15 = lane & 15, g = lane >> 4;

    // stage W (fp32 [64 in][64 out]) -> WtF bf16 transposed+swizzled
#pragma unroll
    for (int p = 0; p < 4; ++p) {
        int idx = p * 256 + t;
        int r = idx >> 4, c4 = (idx & 15) * 4;      // W[in=r][out=c4..c4+3]
        f32x4 wv = *(const f32x4*)&W[(size_t)(h * 64 + r) * 64 + c4];
#pragma unroll
        for (int j = 0; j < 4; ++j) WtF[SWZ(c4 + j, r)] = f2bf(wv[j]);
    }

    // A fragments: x rows -> bf16 (row = w*16 + l15, k = 32c + 8g + e)
    const int row = rt * 64 + w * 16 + l15;
    union { u16x8 u; bf16x8 b; } a0, a1;
    {
        f32x4 x0 = *(const f32x4*)&x[(size_t)row * 64 + g * 8];
        f32x4 x1 = *(const f32x4*)&x[(size_t)row * 64 + g * 8 + 4];
        f32x4 x2 = *(const f32x4*)&x[(size_t)row * 64 + 32 + g * 8];
        f32x4 x3 = *(const f32x4*)&x[(size_t)row * 64 + 32 + g * 8 + 4];
#pragma unroll
        for (int j = 0; j < 4; ++j) {
            a0.u[j] = f2bf(x0[j]); a0.u[4 + j] = f2bf(x1[j]);
            a1.u[j] = f2bf(x2[j]); a1.u[4 + j] = f2bf(x3[j]);
        }
    }
    __syncthreads();

    f32x4 acc[4] = {};
#pragma unroll
    for (int ct = 0; ct < 4; ++ct) {
        bf16x8 b0 = *(const bf16x8*)&WtF[SWZ(ct * 16 + l15, g * 8)];
        bf16x8 b1 = *(const bf16x8*)&WtF[SWZ(ct * 16 + l15, 32 + g * 8)];
        acc[ct] = __builtin_amdgcn_mfma_f32_16x16x32_bf16(a0.b, b0, acc[ct], 0, 0, 0);
        acc[ct] = __builtin_amdgcn_mfma_f32_16x16x32_bf16(a1.b, b1, acc[ct], 0, 0, 0);
    }
    // store: C row = w*16 + 4g + rr, col = ct*16 + l15
#pragma unroll
    for (int ct = 0; ct < 4; ++ct) {
        float bb = bias[h * 64 + ct * 16 + l15];
#pragma unroll
        for (int rr = 0; rr < 4; ++rr) {
            int orow = rt * 64 + w * 16 + g * 4 + rr;
            out[((size_t)h * NT + orow) * 64 + ct * 16 + l15] = f2bf(acc[ct][rr] + bb);
        }
    }
}

// -------------------- K2: causal flash attention (paired + dbuf) -----------
// grid (16 pairs, H, B), block 256 (4 waves). Block processes q-tiles
// {pairid, 31-pairid} sequentially: constant 33 kv-iters/block (no tail).
// K/V double-buffered in LDS; next tile's global loads issued before compute.
__global__ __launch_bounds__(256) void attn_kernel2(
    const uint16_t* __restrict__ qb, const uint16_t* __restrict__ kb,
    const uint16_t* __restrict__ vb, float* __restrict__ cat)
{
    __shared__ uint16_t KsF[2][64 * 72];   // K row-major [key][d], swizzled
    __shared__ uint16_t VtF[2][64 * 72];   // V transposed [d][key], swizzled
    __shared__ uint16_t PsF[4][16 * 72];   // per-wave P [q][key], swizzled
    const int pairid = blockIdx.x, h = blockIdx.y, b = blockIdx.z;
    const int t = threadIdx.x, lane = t & 63, wave = t >> 6;
    const int l15 = lane & 15, g = lane >> 4;
    const size_t base = ((size_t)h * NT + (size_t)b * Tt) * 64;
    const uint16_t* Qh = qb + base;
    const uint16_t* Kh = kb + base;
    const uint16_t* Vh = vb + base;
    const int rS = t >> 3, cS = (t & 7) * 8;   // staging: rows rS / 32+rS

    for (int ph = 0; ph < 2; ++ph) {
        const int qt = ph ? (31 - pairid) : pairid;
        // Q fragments (row = qt*64 + wave*16 + l15, k = 32c + 8g + e)
        bf16x8 aq0, aq1;
        {
            int qrow = qt * 64 + wave * 16 + l15;
            aq0 = *(const bf16x8*)&Qh[(size_t)qrow * 64 + g * 8];
            aq1 = *(const bf16x8*)&Qh[(size_t)qrow * 64 + 32 + g * 8];
        }
        f32x4 o[4] = {};
        float m_run[4], l_run[4];
#pragma unroll
        for (int r = 0; r < 4; ++r) { m_run[r] = -INFINITY; l_run[r] = 0.f; }

        // prologue: stage kv=0 into buffer 0 (barrier first: buffer may still
        // be read by the previous phase's last iteration)
        __syncthreads();
        {
            u16x8 k0 = *(const u16x8*)&Kh[(size_t)(rS) * 64 + cS];
            u16x8 k1 = *(const u16x8*)&Kh[(size_t)(32 + rS) * 64 + cS];
            u16x8 v0 = *(const u16x8*)&Vh[(size_t)(rS) * 64 + cS];
            u16x8 v1 = *(const u16x8*)&Vh[(size_t)(32 + rS) * 64 + cS];
            *(u16x8*)&KsF[0][SWZ(rS, cS)] = k0;
            *(u16x8*)&KsF[0][SWZ(32 + rS, cS)] = k1;
#pragma unroll
            for (int j = 0; j < 8; ++j) {
                VtF[0][SWZ(cS + j, rS)] = v0[j];
                VtF[0][SWZ(cS + j, 32 + rS)] = v1[j];
            }
        }
        __syncthreads();

        for (int kv = 0; kv <= qt; ++kv) {
            const int cur = kv & 1;
            const bool pf = kv < qt;
            u16x8 pk0, pk1, pv0, pv1;
            if (pf) {   // issue next tile's loads early (latency hides under compute)
                int kr = (kv + 1) * 64;
                pk0 = *(const u16x8*)&Kh[(size_t)(kr + rS) * 64 + cS];
                pk1 = *(const u16x8*)&Kh[(size_t)(kr + 32 + rS) * 64 + cS];
                pv0 = *(const u16x8*)&Vh[(size_t)(kr + rS) * 64 + cS];
                pv1 = *(const u16x8*)&Vh[(size_t)(kr + 32 + rS) * 64 + cS];
            }

            // S = Q K^T
            f32x4 s[4];
#pragma unroll
            for (int kt = 0; kt < 4; ++kt) {
                bf16x8 bk0 = *(const bf16x8*)&KsF[cur][SWZ(kt * 16 + l15, g * 8)];
                bf16x8 bk1 = *(const bf16x8*)&KsF[cur][SWZ(kt * 16 + l15, 32 + g * 8)];
                f32x4 z = {};
                z = __builtin_amdgcn_mfma_f32_16x16x32_bf16(aq0, bk0, z, 0, 0, 0);
                z = __builtin_amdgcn_mfma_f32_16x16x32_bf16(aq1, bk1, z, 0, 0, 0);
                s[kt] = z;
            }
            if (kv == qt) {   // causal mask, diagonal tile only
#pragma unroll
                for (int kt = 0; kt < 4; ++kt) {
                    int key = kt * 16 + l15;
#pragma unroll
                    for (int r = 0; r < 4; ++r) {
                        int qr = wave * 16 + g * 4 + r;
                        if (key > qr) s[kt][r] = -INFINITY;
                    }
                }
            }
            // online softmax (row r lives in 16 lanes sharing lane>>4)
            float mt[4];
#pragma unroll
            for (int r = 0; r < 4; ++r) {
                mt[r] = fmaxf(fmaxf(s[0][r], s[1][r]), fmaxf(s[2][r], s[3][r]));
                mt[r] = fmaxf(mt[r], __shfl_xor(mt[r], 1));
                mt[r] = fmaxf(mt[r], __shfl_xor(mt[r], 2));
                mt[r] = fmaxf(mt[r], __shfl_xor(mt[r], 4));
                mt[r] = fmaxf(mt[r], __shfl_xor(mt[r], 8));
            }
            float ls[4];
#pragma unroll
            for (int r = 0; r < 4; ++r) {
                float mnew = fmaxf(m_run[r], mt[r]);
                float alpha = __expf(m_run[r] - mnew);
                m_run[r] = mnew;
                l_run[r] *= alpha;
                o[0][r] *= alpha; o[1][r] *= alpha; o[2][r] *= alpha; o[3][r] *= alpha;
                float sum = 0.f;
#pragma unroll
                for (int kt = 0; kt < 4; ++kt) {
                    float p = __expf(s[kt][r] - mnew);
                    s[kt][r] = p;
                    sum += p;
                }
                ls[r] = sum;
            }
#pragma unroll
            for (int r = 0; r < 4; ++r) {
                ls[r] += __shfl_xor(ls[r], 1);
                ls[r] += __shfl_xor(ls[r], 2);
                ls[r] += __shfl_xor(ls[r], 4);
                ls[r] += __shfl_xor(ls[r], 8);
                l_run[r] += ls[r];
            }
            // P (bf16) -> wave-private LDS (swizzled), read back as A-frags
#pragma unroll
            for (int kt = 0; kt < 4; ++kt)
#pragma unroll
                for (int r = 0; r < 4; ++r)
                    PsF[wave][PSZ(g * 4 + r, kt * 16 + l15)] = f2bf(s[kt][r]);
            // O += P V
#pragma unroll
            for (int c = 0; c < 2; ++c) {
                bf16x8 ap = *(const bf16x8*)&PsF[wave][PSZ(l15, c * 32 + g * 8)];
#pragma unroll
                for (int dt = 0; dt < 4; ++dt) {
                    bf16x8 bv = *(const bf16x8*)&VtF[cur][SWZ(dt * 16 + l15, c * 32 + g * 8)];
                    o[dt] = __builtin_amdgcn_mfma_f32_16x16x32_bf16(ap, bv, o[dt], 0, 0, 0);
                }
            }
            if (pf) {   // write prefetched tile into the other buffer
                *(u16x8*)&KsF[cur ^ 1][SWZ(rS, cS)] = pk0;
                *(u16x8*)&KsF[cur ^ 1][SWZ(32 + rS, cS)] = pk1;
#pragma unroll
                for (int j = 0; j < 8; ++j) {
                    VtF[cur ^ 1][SWZ(cS + j, rS)] = pv0[j];
                    VtF[cur ^ 1][SWZ(cS + j, 32 + rS)] = pv1[j];
                }
                __syncthreads();
            }
        }
        // epilogue: normalize, write concat layout cat[b][t][h*64+d]
        float inv[4];
#pragma unroll
        for (int r = 0; r < 4; ++r) inv[r] = 1.f / l_run[r];
#pragma unroll
        for (int dt = 0; dt < 4; ++dt)
#pragma unroll
            for (int r = 0; r < 4; ++r) {
                int row = qt * 64 + wave * 16 + g * 4 + r;
                cat[((size_t)b * Tt + row) * (Hh * 64) + h * 64 + dt * 16 + l15] =
                    o[dt][r] * inv[r];
            }
    }
}

// -------------------- LayerNorm helper (wave = one row of 64) --------------
__device__ __forceinline__ float wave_ln(float s, float gamma, float beta) {
    float mu = s;
#pragma unroll
    for (int m = 1; m <= 32; m <<= 1) mu += __shfl_xor(mu, m);
    mu *= (1.f / 64.f);
    float d = s - mu;
    float v = d * d;
#pragma unroll
    for (int m = 1; m <= 32; m <<= 1) v += __shfl_xor(v, m);
    v *= (1.f / 64.f);
    return d * rsqrtf(v + 1e-5f) * gamma + beta;
}

// -------------------- K3: proj + residual + LN1 -> h1 ----------------------
// cat[8192x512] @ Wp[512x64] + bp, then h1 = LN(x + .), 512 blocks x 16 rows.
__global__ __launch_bounds__(256) void proj_ln1_kernel(
    const float* __restrict__ cat, const float* __restrict__ Wp,
    const float* __restrict__ bp, const float* __restrict__ x,
    const float* __restrict__ g1, const float* __restrict__ be1,
    float* __restrict__ h1)
{
    __shared__ float cs[16][516];
    __shared__ float wps[128][64];
    __shared__ float ps[16][68];
    const int rt = blockIdx.x;   // 512 blocks x 16 rows
    const int t = threadIdx.x;
#pragma unroll
    for (int p = 0; p < 8; ++p) {
        int idx = p * 256 + t;
        int r = idx >> 7, c4 = (idx & 127) * 4;
        *(f32x4*)&cs[r][c4] = *(const f32x4*)&cat[((size_t)rt * 16 + r) * 512 + c4];
    }
    const int c0 = (t & 31) * 2;
    const int r0 = t >> 5;          // 0..7
    float acc[2][2] = {};
    for (int kt = 0; kt < 4; ++kt) {
        __syncthreads();
#pragma unroll
        for (int p = 0; p < 8; ++p) {
            int idx = p * 256 + t;
            int r = idx >> 4, c4 = (idx & 15) * 4;
            *(f32x4*)&wps[r][c4] = *(const f32x4*)&Wp[(size_t)(kt * 128 + r) * 64 + c4];
        }
        __syncthreads();
#pragma unroll 4
        for (int k = 0; k < 128; ++k) {
            f32x2 w = *(f32x2*)&wps[k][c0];
            float a0 = cs[r0][kt * 128 + k];
            float a1 = cs[r0 + 8][kt * 128 + k];
            acc[0][0] += a0 * w[0]; acc[0][1] += a0 * w[1];
            acc[1][0] += a1 * w[0]; acc[1][1] += a1 * w[1];
        }
    }
    f32x2 bb = *(const f32x2*)&bp[c0];
#pragma unroll
    for (int i = 0; i < 2; ++i) {
        int row = r0 + 8 * i;
        ps[row][c0]     = acc[i][0] + bb[0];
        ps[row][c0 + 1] = acc[i][1] + bb[1];
    }
    __syncthreads();
    // LN1 over the 16 full rows now in LDS
    const int lane = t & 63, wv = t >> 6;
    const float gg = g1[lane], be = be1[lane];
#pragma unroll
    for (int i = 0; i < 4; ++i) {
        int r = wv * 4 + i;
        float s = ps[r][lane] + x[((size_t)rt * 16 + r) * 64 + lane];
        h1[((size_t)rt * 16 + r) * 64 + lane] = wave_ln(s, gg, be);
    }
}

// -------------------- K4: FFN + residual + LN2 -> out ----------------------
__global__ __launch_bounds__(256) void ffn_kernel(
    const float* __restrict__ h1,
    const float* __restrict__ W1, const float* __restrict__ b1,
    const float* __restrict__ W2, const float* __restrict__ b2,
    const float* __restrict__ g2, const float* __restrict__ be2,
    float* __restrict__ out)
{
    __shared__ float w1s[64 * 256];
    __shared__ float w2s[256 * 64];
    __shared__ float hs[16][68];
    __shared__ float hid[16][256];
    const int rt = blockIdx.x;
    const int t = threadIdx.x;
    // W1: 64*256 floats = 4096 f32x4 / 256 threads = 16 iterations (exact).
#pragma unroll
    for (int p = 0; p < 16; ++p) {
        int idx = p * 256 + t;
        ((f32x4*)w1s)[idx] = ((const f32x4*)W1)[idx];
        ((f32x4*)w2s)[idx] = ((const f32x4*)W2)[idx];
    }
    {
        int r = t >> 4, c4 = (t & 15) * 4;
        *(f32x4*)&hs[r][c4] = *(const f32x4*)&h1[((size_t)rt * 16 + r) * 64 + c4];
    }
    __syncthreads();
    // phase 1: hidden[r][t] = relu(h1[r] . W1[:,t] + b1[t])
    {
        float bias = b1[t];
        float acc[16];
#pragma unroll
        for (int r = 0; r < 16; ++r) acc[r] = bias;
#pragma unroll 4
        for (int k = 0; k < 64; ++k) {
            float w = w1s[k * 256 + t];
#pragma unroll
            for (int r = 0; r < 16; ++r) acc[r] += hs[r][k] * w;
        }
#pragma unroll
        for (int r = 0; r < 16; ++r) hid[r][t] = fmaxf(acc[r], 0.f);
    }
    __syncthreads();
    // phase 2: out[r][lane] = LN(h1[r][lane] + hidden[r] . W2[:,lane] + b2)
    const int lane = t & 63, wave = t >> 6;
    const float gg = g2[lane], be = be2[lane], bias2 = b2[lane];
#pragma unroll
    for (int i = 0; i < 4; ++i) {
        int r = wave + 4 * i;
        float a0 = bias2, a1 = 0.f, a2 = 0.f, a3 = 0.f;
#pragma unroll 2
        for (int k = 0; k < 256; k += 4) {
            a0 += hid[r][k]     * w2s[(k)     * 64 + lane];
            a1 += hid[r][k + 1] * w2s[(k + 1) * 64 + lane];
            a2 += hid[r][k + 2] * w2s[(k + 2) * 64 + lane];
            a3 += hid[r][k + 3] * w2s[(k + 3) * 64 + lane];
        }
        float s = (a0 + a1) + (a2 + a3) + hs[r][lane];
        out[((size_t)rt * 16 + r) * 64 + lane] = wave_ln(s, gg, be);
    }
}

// ---------------------------------------------------------------------------
extern "C" void kernel_launch(void* const* d_in, const int* in_sizes, int n_in,
                              void* d_out, int out_size, void* d_ws, size_t ws_size,
                              hipStream_t stream)
{
    (void)in_sizes; (void)n_in; (void)out_size; (void)ws_size;
    const float* x   = (const float*)d_in[0];
    const float* Wq  = (const float*)d_in[1];
    const float* bq  = (const float*)d_in[2];
    const float* Wk  = (const float*)d_in[3];
    const float* bk  = (const float*)d_in[4];
    const float* Wv  = (const float*)d_in[5];
    const float* bv  = (const float*)d_in[6];
    const float* Wp  = (const float*)d_in[7];
    const float* bp  = (const float*)d_in[8];
    const float* W1  = (const float*)d_in[9];
    const float* b1  = (const float*)d_in[10];
    const float* W2  = (const float*)d_in[11];
    const float* b2  = (const float*)d_in[12];
    const float* g1  = (const float*)d_in[13];
    const float* be1 = (const float*)d_in[14];
    const float* g2  = (const float*)d_in[15];
    const float* be2 = (const float*)d_in[16];
    float* outp = (float*)d_out;

    char* w = (char*)d_ws;
    uint16_t* qb = (uint16_t*)w;                       // [H][NT][64] bf16, 8MB
    uint16_t* kb = qb + (size_t)Hh * NT * 64;          // 8MB
    uint16_t* vb = kb + (size_t)Hh * NT * 64;          // 8MB
    float* cat   = (float*)(w + (size_t)3 * Hh * NT * 64 * 2);  // [NT][512] 16MB
    float* h1    = cat + (size_t)NT * 512;             // [NT][64] 2MB

    qkv_kernel<<<dim3(NT / 64, Hh, 3), dim3(256), 0, stream>>>(
        x, Wq, bq, Wk, bk, Wv, bv, qb, kb, vb);
    attn_kernel2<<<dim3(16, Hh, Bb), dim3(256), 0, stream>>>(qb, kb, vb, cat);
    proj_ln1_kernel<<<dim3(NT / 16), dim3(256), 0, stream>>>(
        cat, Wp, bp, x, g1, be1, h1);
    ffn_kernel<<<dim3(NT / 16), dim3(256), 0, stream>>>(
        h1, W1, b1, W2, b2, g2, be2, outp);
}

// Round 5
// 192.188 us; speedup vs baseline: 1.7579x; 1.2539x over previous
//
#include <hip/hip_runtime.h>
#include <hip/hip_bf16.h>
#include <stdint.h>

#define Dd 64
#define Hh 8
#define Bb 4
#define Tt 2048
#define NT (Bb * Tt)   // 8192 token rows

typedef __attribute__((ext_vector_type(4))) float f32x4;
typedef __attribute__((ext_vector_type(8))) __bf16 bf16x8;
typedef __attribute__((ext_vector_type(8))) uint16_t u16x8;

// fp32 -> bf16 via native cast (compiler emits v_cvt_pk_bf16_f32, RTNE).
// Manual bit-math version cost 3-4 VALU ops/element.
__device__ __forceinline__ uint16_t f2bf_fast(float f) {
    union { __bf16 h; uint16_t u; } c; c.h = (__bf16)f; return c.u;
}

// XOR-swizzled LDS layouts for bf16 [col][k] tiles (transposed weights / K / V).
// Element (row,k) -> row*STRIDE + (k ^ (((row>>3)&7)<<3)). Bijective per aligned
// 8-chunk of k, so b128 accesses with the same XOR stay contiguous; spreads the
// scalar transpose-write lanes (which differ in row by 8,16,..) across banks.
#define SWZ(row, k)   ((row) * 72  + ((k) ^ ((((row) >> 3) & 7) << 3)))   // k<64
#define PSZ(q, k)     ((q)  * 72  + ((k) ^ ((((q)  >> 2) & 3) << 3)))    // 16xq
#define W2SWZ(col, k) ((col) * 264 + ((k) ^ ((((col) >> 3) & 7) << 3)))  // k<256
#define WPSWZ(col, k) ((col) * 520 + ((k) ^ ((((col) >> 3) & 7) << 3)))  // k<512

// -------------------- K1: per-head QKV projections (bf16 MFMA) -------------
// grid (128 row-tiles, H, 3 mats), block 256 (4 waves).
__global__ __launch_bounds__(256) void qkv_kernel(
    const float* __restrict__ x,
    const float* __restrict__ Wq, const float* __restrict__ bq,
    const float* __restrict__ Wk, const float* __restrict__ bk,
    const float* __restrict__ Wv, const float* __restrict__ bv,
    uint16_t* __restrict__ qb, uint16_t* __restrict__ kb, uint16_t* __restrict__ vb)
{
    __shared__ uint16_t WtF[64 * 72];   // W^T bf16 swizzled: (out, in)
    const int rt = blockIdx.x, h = blockIdx.y, m = blockIdx.z;
    const float* W    = (m == 0) ? Wq : (m == 1) ? Wk : Wv;
    const float* bias = (m == 0) ? bq : (m == 1) ? bk : bv;
    uint16_t*    out  = (m == 0) ? qb : (m == 1) ? kb : vb;
    const int t = threadIdx.x, lane = t & 63, w = t >> 6;
    const int l15 = lane & 15, g = lane >> 4;

#pragma unroll
    for (int p = 0; p < 4; ++p) {
        int idx = p * 256 + t;
        int r = idx >> 4, c4 = (idx & 15) * 4;      // W[in=r][out=c4..c4+3]
        f32x4 wv = *(const f32x4*)&W[(size_t)(h * 64 + r) * 64 + c4];
#pragma unroll
        for (int j = 0; j < 4; ++j) WtF[SWZ(c4 + j, r)] = f2bf_fast(wv[j]);
    }

    const int row = rt * 64 + w * 16 + l15;
    union { u16x8 u; bf16x8 b; } a0, a1;
    {
        f32x4 x0 = *(const f32x4*)&x[(size_t)row * 64 + g * 8];
        f32x4 x1 = *(const f32x4*)&x[(size_t)row * 64 + g * 8 + 4];
        f32x4 x2 = *(const f32x4*)&x[(size_t)row * 64 + 32 + g * 8];
        f32x4 x3 = *(const f32x4*)&x[(size_t)row * 64 + 32 + g * 8 + 4];
#pragma unroll
        for (int j = 0; j < 4; ++j) {
            a0.u[j] = f2bf_fast(x0[j]); a0.u[4 + j] = f2bf_fast(x1[j]);
            a1.u[j] = f2bf_fast(x2[j]); a1.u[4 + j] = f2bf_fast(x3[j]);
        }
    }
    __syncthreads();

    f32x4 acc[4] = {};
#pragma unroll
    for (int ct = 0; ct < 4; ++ct) {
        bf16x8 b0 = *(const bf16x8*)&WtF[SWZ(ct * 16 + l15, g * 8)];
        bf16x8 b1 = *(const bf16x8*)&WtF[SWZ(ct * 16 + l15, 32 + g * 8)];
        acc[ct] = __builtin_amdgcn_mfma_f32_16x16x32_bf16(a0.b, b0, acc[ct], 0, 0, 0);
        acc[ct] = __builtin_amdgcn_mfma_f32_16x16x32_bf16(a1.b, b1, acc[ct], 0, 0, 0);
    }
#pragma unroll
    for (int ct = 0; ct < 4; ++ct) {
        float bb = bias[h * 64 + ct * 16 + l15];
#pragma unroll
        for (int rr = 0; rr < 4; ++rr) {
            int orow = rt * 64 + w * 16 + g * 4 + rr;
            out[((size_t)h * NT + orow) * 64 + ct * 16 + l15] =
                f2bf_fast(acc[ct][rr] + bb);
        }
    }
}

// -------------------- K2: causal flash attention (paired+dbuf+defer-max) ---
// grid (16 pairs, H, B), block 256 (4 waves); q-tiles {p, 31-p} per block.
// Writes bf16 into concat layout cat[b][t][h*64+d].
__global__ __launch_bounds__(256) void attn_kernel3(
    const uint16_t* __restrict__ qb, const uint16_t* __restrict__ kb,
    const uint16_t* __restrict__ vb, uint16_t* __restrict__ cat)
{
    __shared__ uint16_t KsF[2][64 * 72];
    __shared__ uint16_t VtF[2][64 * 72];
    __shared__ uint16_t PsF[4][16 * 72];
    const int pairid = blockIdx.x, h = blockIdx.y, b = blockIdx.z;
    const int t = threadIdx.x, lane = t & 63, wave = t >> 6;
    const int l15 = lane & 15, g = lane >> 4;
    const size_t base = ((size_t)h * NT + (size_t)b * Tt) * 64;
    const uint16_t* Qh = qb + base;
    const uint16_t* Kh = kb + base;
    const uint16_t* Vh = vb + base;
    const int rS = t >> 3, cS = (t & 7) * 8;

    for (int ph = 0; ph < 2; ++ph) {
        const int qt = ph ? (31 - pairid) : pairid;
        bf16x8 aq0, aq1;
        {
            int qrow = qt * 64 + wave * 16 + l15;
            aq0 = *(const bf16x8*)&Qh[(size_t)qrow * 64 + g * 8];
            aq1 = *(const bf16x8*)&Qh[(size_t)qrow * 64 + 32 + g * 8];
        }
        f32x4 o[4] = {};
        float m_run[4], l_run[4];
#pragma unroll
        for (int r = 0; r < 4; ++r) { m_run[r] = -INFINITY; l_run[r] = 0.f; }

        __syncthreads();
        {
            u16x8 k0 = *(const u16x8*)&Kh[(size_t)(rS) * 64 + cS];
            u16x8 k1 = *(const u16x8*)&Kh[(size_t)(32 + rS) * 64 + cS];
            u16x8 v0 = *(const u16x8*)&Vh[(size_t)(rS) * 64 + cS];
            u16x8 v1 = *(const u16x8*)&Vh[(size_t)(32 + rS) * 64 + cS];
            *(u16x8*)&KsF[0][SWZ(rS, cS)] = k0;
            *(u16x8*)&KsF[0][SWZ(32 + rS, cS)] = k1;
#pragma unroll
            for (int j = 0; j < 8; ++j) {
                VtF[0][SWZ(cS + j, rS)] = v0[j];
                VtF[0][SWZ(cS + j, 32 + rS)] = v1[j];
            }
        }
        __syncthreads();

        for (int kv = 0; kv <= qt; ++kv) {
            const int cur = kv & 1;
            const bool pf = kv < qt;
            u16x8 pk0, pk1, pv0, pv1;
            if (pf) {
                int kr = (kv + 1) * 64;
                pk0 = *(const u16x8*)&Kh[(size_t)(kr + rS) * 64 + cS];
                pk1 = *(const u16x8*)&Kh[(size_t)(kr + 32 + rS) * 64 + cS];
                pv0 = *(const u16x8*)&Vh[(size_t)(kr + rS) * 64 + cS];
                pv1 = *(const u16x8*)&Vh[(size_t)(kr + 32 + rS) * 64 + cS];
            }
            // S = Q K^T
            f32x4 s[4];
#pragma unroll
            for (int kt = 0; kt < 4; ++kt) {
                bf16x8 bk0 = *(const bf16x8*)&KsF[cur][SWZ(kt * 16 + l15, g * 8)];
                bf16x8 bk1 = *(const bf16x8*)&KsF[cur][SWZ(kt * 16 + l15, 32 + g * 8)];
                f32x4 z = {};
                z = __builtin_amdgcn_mfma_f32_16x16x32_bf16(aq0, bk0, z, 0, 0, 0);
                z = __builtin_amdgcn_mfma_f32_16x16x32_bf16(aq1, bk1, z, 0, 0, 0);
                s[kt] = z;
            }
            if (kv == qt) {
#pragma unroll
                for (int kt = 0; kt < 4; ++kt) {
                    int key = kt * 16 + l15;
#pragma unroll
                    for (int r = 0; r < 4; ++r) {
                        int qr = wave * 16 + g * 4 + r;
                        if (key > qr) s[kt][r] = -INFINITY;
                    }
                }
            }
            // row max (16-lane groups)
            float mt[4];
#pragma unroll
            for (int r = 0; r < 4; ++r) {
                mt[r] = fmaxf(fmaxf(s[0][r], s[1][r]), fmaxf(s[2][r], s[3][r]));
                mt[r] = fmaxf(mt[r], __shfl_xor(mt[r], 1));
                mt[r] = fmaxf(mt[r], __shfl_xor(mt[r], 2));
                mt[r] = fmaxf(mt[r], __shfl_xor(mt[r], 4));
                mt[r] = fmaxf(mt[r], __shfl_xor(mt[r], 8));
            }
            // defer-max (T13): only rescale when some row's max grew > 8.
            // Skipping keeps m_run; P bounded by e^8, fp32 l/o absorb it.
            bool need = false;
#pragma unroll
            for (int r = 0; r < 4; ++r) need |= (mt[r] > m_run[r] + 8.f);
            if (__any((int)need)) {
#pragma unroll
                for (int r = 0; r < 4; ++r) {
                    float mnew = fmaxf(m_run[r], mt[r]);
                    float a = __expf(m_run[r] - mnew);
                    m_run[r] = mnew;
                    l_run[r] *= a;
                    o[0][r] *= a; o[1][r] *= a; o[2][r] *= a; o[3][r] *= a;
                }
            }
            float ls[4];
#pragma unroll
            for (int r = 0; r < 4; ++r) {
                float sum = 0.f;
#pragma unroll
                for (int kt = 0; kt < 4; ++kt) {
                    float p = __expf(s[kt][r] - m_run[r]);
                    s[kt][r] = p;
                    sum += p;
                }
                ls[r] = sum;
            }
#pragma unroll
            for (int r = 0; r < 4; ++r) {
                ls[r] += __shfl_xor(ls[r], 1);
                ls[r] += __shfl_xor(ls[r], 2);
                ls[r] += __shfl_xor(ls[r], 4);
                ls[r] += __shfl_xor(ls[r], 8);
                l_run[r] += ls[r];
            }
#pragma unroll
            for (int kt = 0; kt < 4; ++kt)
#pragma unroll
                for (int r = 0; r < 4; ++r)
                    PsF[wave][PSZ(g * 4 + r, kt * 16 + l15)] = f2bf_fast(s[kt][r]);
            // O += P V
#pragma unroll
            for (int c = 0; c < 2; ++c) {
                bf16x8 ap = *(const bf16x8*)&PsF[wave][PSZ(l15, c * 32 + g * 8)];
#pragma unroll
                for (int dt = 0; dt < 4; ++dt) {
                    bf16x8 bv = *(const bf16x8*)&VtF[cur][SWZ(dt * 16 + l15, c * 32 + g * 8)];
                    o[dt] = __builtin_amdgcn_mfma_f32_16x16x32_bf16(ap, bv, o[dt], 0, 0, 0);
                }
            }
            if (pf) {
                *(u16x8*)&KsF[cur ^ 1][SWZ(rS, cS)] = pk0;
                *(u16x8*)&KsF[cur ^ 1][SWZ(32 + rS, cS)] = pk1;
#pragma unroll
                for (int j = 0; j < 8; ++j) {
                    VtF[cur ^ 1][SWZ(cS + j, rS)] = pv0[j];
                    VtF[cur ^ 1][SWZ(cS + j, 32 + rS)] = pv1[j];
                }
                __syncthreads();
            }
        }
        float inv[4];
#pragma unroll
        for (int r = 0; r < 4; ++r) inv[r] = 1.f / l_run[r];
#pragma unroll
        for (int dt = 0; dt < 4; ++dt)
#pragma unroll
            for (int r = 0; r < 4; ++r) {
                int row = qt * 64 + wave * 16 + g * 4 + r;
                cat[((size_t)b * Tt + row) * (Hh * 64) + h * 64 + dt * 16 + l15] =
                    f2bf_fast(o[dt][r] * inv[r]);
            }
    }
}

// -------------------- K3: proj (MFMA) + residual + LN1 -> h1, h1b ----------
// cat[8192x512]bf16 @ Wp[512x64] + bp; h1 = LN(x + .). 128 blocks x 64 rows.
__global__ __launch_bounds__(256) void proj_ln1_mfma(
    const uint16_t* __restrict__ cat, const float* __restrict__ Wp,
    const float* __restrict__ bp, const float* __restrict__ x,
    const float* __restrict__ g1, const float* __restrict__ be1,
    float* __restrict__ h1, uint16_t* __restrict__ h1b)
{
    __shared__ uint16_t WptF[64 * 520];   // Wp^T bf16 swizzled, 66.6 KB
    const int rt = blockIdx.x;
    const int t = threadIdx.x, lane = t & 63, w = t >> 6;
    const int l15 = lane & 15, g = lane >> 4;
#pragma unroll
    for (int p = 0; p < 32; ++p) {
        int idx = p * 256 + t;
        int r = idx >> 4, c4 = (idx & 15) * 4;     // Wp[k=r][col=c4..]
        f32x4 wv = *(const f32x4*)&Wp[(size_t)r * 64 + c4];
#pragma unroll
        for (int j = 0; j < 4; ++j) WptF[WPSWZ(c4 + j, r)] = f2bf_fast(wv[j]);
    }
    __syncthreads();
    const int arow = rt * 64 + w * 16 + l15;
    f32x4 acc[4] = {};
#pragma unroll
    for (int kt = 0; kt < 16; ++kt) {
        bf16x8 a = *(const bf16x8*)&cat[(size_t)arow * 512 + kt * 32 + g * 8];
#pragma unroll
        for (int ct = 0; ct < 4; ++ct) {
            bf16x8 bfr = *(const bf16x8*)&WptF[WPSWZ(ct * 16 + l15, kt * 32 + g * 8)];
            acc[ct] = __builtin_amdgcn_mfma_f32_16x16x32_bf16(a, bfr, acc[ct], 0, 0, 0);
        }
    }
    // epilogue: bias + residual + LN1 (D rows = w*16 + g*4 + rr, col = ct*16+l15)
    float bpv[4], g1v[4], b1v[4];
#pragma unroll
    for (int ct = 0; ct < 4; ++ct) {
        bpv[ct] = bp[ct * 16 + l15];
        g1v[ct] = g1[ct * 16 + l15];
        b1v[ct] = be1[ct * 16 + l15];
    }
#pragma unroll
    for (int rr = 0; rr < 4; ++rr) {
        int drow = rt * 64 + w * 16 + g * 4 + rr;
        float s[4], sum = 0.f;
#pragma unroll
        for (int ct = 0; ct < 4; ++ct) {
            s[ct] = acc[ct][rr] + bpv[ct] + x[(size_t)drow * 64 + ct * 16 + l15];
            sum += s[ct];
        }
        sum += __shfl_xor(sum, 1); sum += __shfl_xor(sum, 2);
        sum += __shfl_xor(sum, 4); sum += __shfl_xor(sum, 8);
        float mu = sum * (1.f / 64.f);
        float v = 0.f;
#pragma unroll
        for (int ct = 0; ct < 4; ++ct) { s[ct] -= mu; v += s[ct] * s[ct]; }
        v += __shfl_xor(v, 1); v += __shfl_xor(v, 2);
        v += __shfl_xor(v, 4); v += __shfl_xor(v, 8);
        float rstd = rsqrtf(v * (1.f / 64.f) + 1e-5f);
#pragma unroll
        for (int ct = 0; ct < 4; ++ct) {
            float hv = s[ct] * rstd * g1v[ct] + b1v[ct];
            h1 [(size_t)drow * 64 + ct * 16 + l15] = hv;
            h1b[(size_t)drow * 64 + ct * 16 + l15] = f2bf_fast(hv);
        }
    }
}

// -------------------- K4: FFN (MFMA x2) + residual + LN2 -> out ------------
// 128 blocks x 64 rows; W1^T/W2^T bf16 staged once; hid via wave-private LDS.
__global__ __launch_bounds__(256) void ffn_mfma(
    const uint16_t* __restrict__ h1b, const float* __restrict__ h1,
    const float* __restrict__ W1, const float* __restrict__ b1,
    const float* __restrict__ W2, const float* __restrict__ b2,
    const float* __restrict__ g2, const float* __restrict__ be2,
    float* __restrict__ out)
{
    __shared__ uint16_t W1t[256 * 72];       // 36 KB  [col<256][k<64]
    __shared__ uint16_t W2t[64 * 264];       // 33.8 KB [col<64][k<256]
    __shared__ uint16_t hidS[4][16 * 264];   // 33.8 KB wave-private [q][k]
    const int rt = blockIdx.x;
    const int t = threadIdx.x, lane = t & 63, w = t >> 6;
    const int l15 = lane & 15, g = lane >> 4;
    // stage W1 [64][256] -> W1t (transposed bf16)
#pragma unroll
    for (int p = 0; p < 16; ++p) {
        int idx = p * 256 + t;
        int r = idx >> 6, c4 = (idx & 63) * 4;
        f32x4 wv = *(const f32x4*)&W1[(size_t)r * 256 + c4];
#pragma unroll
        for (int j = 0; j < 4; ++j) W1t[SWZ(c4 + j, r)] = f2bf_fast(wv[j]);
    }
    // stage W2 [256][64] -> W2t
#pragma unroll
    for (int p = 0; p < 16; ++p) {
        int idx = p * 256 + t;
        int r = idx >> 4, c4 = (idx & 15) * 4;
        f32x4 wv = *(const f32x4*)&W2[(size_t)r * 64 + c4];
#pragma unroll
        for (int j = 0; j < 4; ++j) W2t[W2SWZ(c4 + j, r)] = f2bf_fast(wv[j]);
    }
    __syncthreads();
    const int arow = rt * 64 + w * 16 + l15;
    // phase 1: hid[16 rows][256] = relu(h1b @ W1 + b1)
    f32x4 acc1[16] = {};
#pragma unroll
    for (int ks = 0; ks < 2; ++ks) {
        bf16x8 a = *(const bf16x8*)&h1b[(size_t)arow * 64 + ks * 32 + g * 8];
#pragma unroll
        for (int ct = 0; ct < 16; ++ct) {
            bf16x8 bfr = *(const bf16x8*)&W1t[SWZ(ct * 16 + l15, ks * 32 + g * 8)];
            acc1[ct] = __builtin_amdgcn_mfma_f32_16x16x32_bf16(a, bfr, acc1[ct], 0, 0, 0);
        }
    }
#pragma unroll
    for (int ct = 0; ct < 16; ++ct) {
        float bb = b1[ct * 16 + l15];
#pragma unroll
        for (int rr = 0; rr < 4; ++rr)
            hidS[w][(g * 4 + rr) * 264 + ct * 16 + l15] =
                f2bf_fast(fmaxf(acc1[ct][rr] + bb, 0.f));
    }
    // wave-private LDS: same-wave write->read, compiler inserts lgkmcnt waits.
    // phase 2: out16x64 = hid @ W2
    f32x4 acc2[4] = {};
#pragma unroll
    for (int ks = 0; ks < 8; ++ks) {
        bf16x8 a = *(const bf16x8*)&hidS[w][l15 * 264 + ks * 32 + g * 8];
#pragma unroll
        for (int ct = 0; ct < 4; ++ct) {
            bf16x8 bfr = *(const bf16x8*)&W2t[W2SWZ(ct * 16 + l15, ks * 32 + g * 8)];
            acc2[ct] = __builtin_amdgcn_mfma_f32_16x16x32_bf16(a, bfr, acc2[ct], 0, 0, 0);
        }
    }
    // epilogue: + b2 + residual h1 + LN2
    float b2v[4], g2v[4], be2v[4];
#pragma unroll
    for (int ct = 0; ct < 4; ++ct) {
        b2v[ct]  = b2[ct * 16 + l15];
        g2v[ct]  = g2[ct * 16 + l15];
        be2v[ct] = be2[ct * 16 + l15];
    }
#pragma unroll
    for (int rr = 0; rr < 4; ++rr) {
        int drow = rt * 64 + w * 16 + g * 4 + rr;
        float s[4], sum = 0.f;
#pragma unroll
        for (int ct = 0; ct < 4; ++ct) {
            s[ct] = acc2[ct][rr] + b2v[ct] + h1[(size_t)drow * 64 + ct * 16 + l15];
            sum += s[ct];
        }
        sum += __shfl_xor(sum, 1); sum += __shfl_xor(sum, 2);
        sum += __shfl_xor(sum, 4); sum += __shfl_xor(sum, 8);
        float mu = sum * (1.f / 64.f);
        float v = 0.f;
#pragma unroll
        for (int ct = 0; ct < 4; ++ct) { s[ct] -= mu; v += s[ct] * s[ct]; }
        v += __shfl_xor(v, 1); v += __shfl_xor(v, 2);
        v += __shfl_xor(v, 4); v += __shfl_xor(v, 8);
        float rstd = rsqrtf(v * (1.f / 64.f) + 1e-5f);
#pragma unroll
        for (int ct = 0; ct < 4; ++ct)
            out[(size_t)drow * 64 + ct * 16 + l15] =
                s[ct] * rstd * g2v[ct] + be2v[ct];
    }
}

// ---------------------------------------------------------------------------
extern "C" void kernel_launch(void* const* d_in, const int* in_sizes, int n_in,
                              void* d_out, int out_size, void* d_ws, size_t ws_size,
                              hipStream_t stream)
{
    (void)in_sizes; (void)n_in; (void)out_size; (void)ws_size;
    const float* x   = (const float*)d_in[0];
    const float* Wq  = (const float*)d_in[1];
    const float* bq  = (const float*)d_in[2];
    const float* Wk  = (const float*)d_in[3];
    const float* bk  = (const float*)d_in[4];
    const float* Wv  = (const float*)d_in[5];
    const float* bv  = (const float*)d_in[6];
    const float* Wp  = (const float*)d_in[7];
    const float* bp  = (const float*)d_in[8];
    const float* W1  = (const float*)d_in[9];
    const float* b1  = (const float*)d_in[10];
    const float* W2  = (const float*)d_in[11];
    const float* b2  = (const float*)d_in[12];
    const float* g1  = (const float*)d_in[13];
    const float* be1 = (const float*)d_in[14];
    const float* g2  = (const float*)d_in[15];
    const float* be2 = (const float*)d_in[16];
    float* outp = (float*)d_out;

    char* w = (char*)d_ws;
    uint16_t* qb  = (uint16_t*)w;                      // [H][NT][64] bf16, 8MB
    uint16_t* kb  = qb + (size_t)Hh * NT * 64;         // 8MB
    uint16_t* vb  = kb + (size_t)Hh * NT * 64;         // 8MB
    uint16_t* cat = vb + (size_t)Hh * NT * 64;         // [NT][512] bf16, 8MB
    float*    h1  = (float*)(cat + (size_t)NT * 512);  // [NT][64] fp32, 2MB
    uint16_t* h1b = (uint16_t*)(h1 + (size_t)NT * 64); // [NT][64] bf16, 1MB

    qkv_kernel<<<dim3(NT / 64, Hh, 3), dim3(256), 0, stream>>>(
        x, Wq, bq, Wk, bk, Wv, bv, qb, kb, vb);
    attn_kernel3<<<dim3(16, Hh, Bb), dim3(256), 0, stream>>>(qb, kb, vb, cat);
    proj_ln1_mfma<<<dim3(NT / 64), dim3(256), 0, stream>>>(
        cat, Wp, bp, x, g1, be1, h1, h1b);
    ffn_mfma<<<dim3(NT / 64), dim3(256), 0, stream>>>(
        h1b, h1, W1, b1, W2, b2, g2, be2, outp);
}

// Round 6
// 185.287 us; speedup vs baseline: 1.8234x; 1.0372x over previous
//
#include <hip/hip_runtime.h>
#include <hip/hip_bf16.h>
#include <stdint.h>

#define Dd 64
#define Hh 8
#define Bb 4
#define Tt 2048
#define NT (Bb * Tt)   // 8192 token rows

typedef __attribute__((ext_vector_type(4))) float f32x4;
typedef __attribute__((ext_vector_type(8))) __bf16 bf16x8;
typedef __attribute__((ext_vector_type(8))) uint16_t u16x8;

// fp32 -> bf16 via native cast (compiler emits v_cvt_pk_bf16_f32, RTNE).
__device__ __forceinline__ uint16_t f2bf_fast(float f) {
    union { __bf16 h; uint16_t u; } c; c.h = (__bf16)f; return c.u;
}

// XOR-swizzled layouts for bf16 [col][k] tiles (transposed weights / K / V).
// Element (row,k) -> row*STRIDE + (k ^ (((row>>3)&7)<<3)). Bijective per aligned
// 8-chunk of k, so b128 accesses with the same XOR stay contiguous; spreads
// transpose-write / fragment-read lanes across banks. The SAME index math is
// used for the pre-swizzled global copies (setup kernel) and the LDS reads, so
// GEMM-kernel staging is a straight linear u16x8 copy.
#define SWZ(row, k)   ((row) * 72  + ((k) ^ ((((row) >> 3) & 7) << 3)))   // k<64
#define PSZ(q, k)     ((q)  * 72  + ((k) ^ ((((q)  >> 2) & 3) << 3)))    // 16xq
#define W2SWZ(col, k) ((col) * 264 + ((k) ^ ((((col) >> 3) & 7) << 3)))  // k<256
#define WPSWZ(col, k) ((col) * 520 + ((k) ^ ((((col) >> 3) & 7) << 3)))  // k<512

// -------------------- K0: one-time conversions into workspace --------------
// blocks [0,256): x -> xb bf16          (8 elts/thread)
// blocks [256,280): Wq/Wk/Wv -> WtAll   (per (m,h): 64x64 transposed+SWZ)
// blocks [280,288): Wp -> WptS          (64 cols x 512 k, WPSWZ)
// blocks [288,292): W1 -> W1g           (256 cols x 64 k, SWZ)
// blocks [292,296): W2 -> W2g           (64 cols x 256 k, W2SWZ)
__global__ __launch_bounds__(256) void setup_kernel(
    const float* __restrict__ x,
    const float* __restrict__ Wq, const float* __restrict__ Wk,
    const float* __restrict__ Wv, const float* __restrict__ Wp,
    const float* __restrict__ W1, const float* __restrict__ W2,
    uint16_t* __restrict__ xb, uint16_t* __restrict__ WtAll,
    uint16_t* __restrict__ WptS, uint16_t* __restrict__ W1g,
    uint16_t* __restrict__ W2g)
{
    const int bid = blockIdx.x, t = threadIdx.x;
    if (bid < 256) {
        size_t base = ((size_t)bid * 256 + t) * 8;
        f32x4 a = *(const f32x4*)&x[base];
        f32x4 b = *(const f32x4*)&x[base + 4];
        u16x8 o;
#pragma unroll
        for (int j = 0; j < 4; ++j) { o[j] = f2bf_fast(a[j]); o[4 + j] = f2bf_fast(b[j]); }
        *(u16x8*)&xb[base] = o;
    } else if (bid < 280) {
        const int mh = bid - 256, m = mh / 8, h = mh % 8;
        const float* W = (m == 0) ? Wq : (m == 1) ? Wk : Wv;
        uint16_t* dst = WtAll + (size_t)mh * 4608;
#pragma unroll
        for (int p = 0; p < 4; ++p) {
            int idx = p * 256 + t;
            int k = idx >> 4, c4 = (idx & 15) * 4;
            f32x4 wv = *(const f32x4*)&W[(size_t)(h * 64 + k) * 64 + c4];
#pragma unroll
            for (int j = 0; j < 4; ++j) dst[SWZ(c4 + j, k)] = f2bf_fast(wv[j]);
        }
    } else if (bid < 288) {
        const int j = bid - 280;           // k-chunk of 64
#pragma unroll
        for (int p = 0; p < 16; ++p) {
            int idx = p * 256 + t;
            int col = idx & 63, k = j * 64 + (idx >> 6);
            WptS[WPSWZ(col, k)] = f2bf_fast(Wp[(size_t)k * 64 + col]);
        }
    } else if (bid < 292) {
        const int j = bid - 288;
#pragma unroll
        for (int p = 0; p < 16; ++p) {
            int e = j * 4096 + p * 256 + t;
            int col = e & 255, k = e >> 8;
            W1g[SWZ(col, k)] = f2bf_fast(W1[(size_t)k * 256 + col]);
        }
    } else {
        const int j = bid - 292;
#pragma unroll
        for (int p = 0; p < 16; ++p) {
            int e = j * 4096 + p * 256 + t;
            int col = e & 63, k = e >> 6;
            W2g[W2SWZ(col, k)] = f2bf_fast(W2[(size_t)k * 64 + col]);
        }
    }
}

// -------------------- K1: per-head QKV projections (bf16 MFMA) -------------
// grid (128 row-tiles, H, 3 mats), block 256 (4 waves). Staging = linear copy.
__global__ __launch_bounds__(256) void qkv_kernel(
    const uint16_t* __restrict__ xb, const uint16_t* __restrict__ WtAll,
    const float* __restrict__ bq, const float* __restrict__ bk,
    const float* __restrict__ bv,
    uint16_t* __restrict__ qb, uint16_t* __restrict__ kb, uint16_t* __restrict__ vb)
{
    __shared__ uint16_t WtF[64 * 72];
    const int rt = blockIdx.x, h = blockIdx.y, m = blockIdx.z;
    const float* bias = (m == 0) ? bq : (m == 1) ? bk : bv;
    uint16_t*    out  = (m == 0) ? qb : (m == 1) ? kb : vb;
    const int t = threadIdx.x, lane = t & 63, w = t >> 6;
    const int l15 = lane & 15, g = lane >> 4;

    {   // 4608 u16 = 576 u16x8, pre-swizzled in global -> linear vector copy
        const u16x8* src = (const u16x8*)(WtAll + (size_t)(m * 8 + h) * 4608);
        u16x8* dst = (u16x8*)WtF;
        dst[t] = src[t];
        dst[256 + t] = src[256 + t];
        if (t < 64) dst[512 + t] = src[512 + t];
    }
    const int row = rt * 64 + w * 16 + l15;
    bf16x8 a0 = *(const bf16x8*)&xb[(size_t)row * 64 + g * 8];
    bf16x8 a1 = *(const bf16x8*)&xb[(size_t)row * 64 + 32 + g * 8];
    __syncthreads();

    f32x4 acc[4] = {};
#pragma unroll
    for (int ct = 0; ct < 4; ++ct) {
        bf16x8 b0 = *(const bf16x8*)&WtF[SWZ(ct * 16 + l15, g * 8)];
        bf16x8 b1 = *(const bf16x8*)&WtF[SWZ(ct * 16 + l15, 32 + g * 8)];
        acc[ct] = __builtin_amdgcn_mfma_f32_16x16x32_bf16(a0, b0, acc[ct], 0, 0, 0);
        acc[ct] = __builtin_amdgcn_mfma_f32_16x16x32_bf16(a1, b1, acc[ct], 0, 0, 0);
    }
#pragma unroll
    for (int ct = 0; ct < 4; ++ct) {
        float bb = bias[h * 64 + ct * 16 + l15];
#pragma unroll
        for (int rr = 0; rr < 4; ++rr) {
            int orow = rt * 64 + w * 16 + g * 4 + rr;
            out[((size_t)h * NT + orow) * 64 + ct * 16 + l15] =
                f2bf_fast(acc[ct][rr] + bb);
        }
    }
}

// -------------------- K2: causal flash attention (XCD-swizzled) ------------
// 512 blocks 1D. lbid = (bid%8)*64 + bid/8 puts lbid-contiguous blocks on one
// XCD (HW round-robins consecutive bid across XCDs): the 16 pair-blocks of
// each (h,b) -- sharing 512KB K/V -- plus 3 more groups land in one XCD's
// 4MB L2. K/V prefetches become L2 hits instead of 8x-duplicated HBM misses.
__global__ __launch_bounds__(256) void attn_kernel4(
    const uint16_t* __restrict__ qb, const uint16_t* __restrict__ kb,
    const uint16_t* __restrict__ vb, uint16_t* __restrict__ cat)
{
    __shared__ uint16_t KsF[2][64 * 72];
    __shared__ uint16_t VtF[2][64 * 72];
    __shared__ uint16_t PsF[4][16 * 72];
    const int bid = blockIdx.x;
    const int lbid = (bid & 7) * 64 + (bid >> 3);   // bijective, 512%8==0
    const int pairid = lbid & 15;
    const int hb = lbid >> 4;
    const int h = hb & 7, b = hb >> 3;
    const int t = threadIdx.x, lane = t & 63, wave = t >> 6;
    const int l15 = lane & 15, g = lane >> 4;
    const size_t base = ((size_t)h * NT + (size_t)b * Tt) * 64;
    const uint16_t* Qh = qb + base;
    const uint16_t* Kh = kb + base;
    const uint16_t* Vh = vb + base;
    const int rS = t >> 3, cS = (t & 7) * 8;

    for (int ph = 0; ph < 2; ++ph) {
        const int qt = ph ? (31 - pairid) : pairid;
        bf16x8 aq0, aq1;
        {
            int qrow = qt * 64 + wave * 16 + l15;
            aq0 = *(const bf16x8*)&Qh[(size_t)qrow * 64 + g * 8];
            aq1 = *(const bf16x8*)&Qh[(size_t)qrow * 64 + 32 + g * 8];
        }
        f32x4 o[4] = {};
        float m_run[4], l_run[4];
#pragma unroll
        for (int r = 0; r < 4; ++r) { m_run[r] = -INFINITY; l_run[r] = 0.f; }

        __syncthreads();
        {
            u16x8 k0 = *(const u16x8*)&Kh[(size_t)(rS) * 64 + cS];
            u16x8 k1 = *(const u16x8*)&Kh[(size_t)(32 + rS) * 64 + cS];
            u16x8 v0 = *(const u16x8*)&Vh[(size_t)(rS) * 64 + cS];
            u16x8 v1 = *(const u16x8*)&Vh[(size_t)(32 + rS) * 64 + cS];
            *(u16x8*)&KsF[0][SWZ(rS, cS)] = k0;
            *(u16x8*)&KsF[0][SWZ(32 + rS, cS)] = k1;
#pragma unroll
            for (int j = 0; j < 8; ++j) {
                VtF[0][SWZ(cS + j, rS)] = v0[j];
                VtF[0][SWZ(cS + j, 32 + rS)] = v1[j];
            }
        }
        __syncthreads();

        for (int kv = 0; kv <= qt; ++kv) {
            const int cur = kv & 1;
            const bool pf = kv < qt;
            u16x8 pk0, pk1, pv0, pv1;
            if (pf) {
                int kr = (kv + 1) * 64;
                pk0 = *(const u16x8*)&Kh[(size_t)(kr + rS) * 64 + cS];
                pk1 = *(const u16x8*)&Kh[(size_t)(kr + 32 + rS) * 64 + cS];
                pv0 = *(const u16x8*)&Vh[(size_t)(kr + rS) * 64 + cS];
                pv1 = *(const u16x8*)&Vh[(size_t)(kr + 32 + rS) * 64 + cS];
            }
            // S = Q K^T
            f32x4 s[4];
#pragma unroll
            for (int kt = 0; kt < 4; ++kt) {
                bf16x8 bk0 = *(const bf16x8*)&KsF[cur][SWZ(kt * 16 + l15, g * 8)];
                bf16x8 bk1 = *(const bf16x8*)&KsF[cur][SWZ(kt * 16 + l15, 32 + g * 8)];
                f32x4 z = {};
                z = __builtin_amdgcn_mfma_f32_16x16x32_bf16(aq0, bk0, z, 0, 0, 0);
                z = __builtin_amdgcn_mfma_f32_16x16x32_bf16(aq1, bk1, z, 0, 0, 0);
                s[kt] = z;
            }
            if (kv == qt) {
#pragma unroll
                for (int kt = 0; kt < 4; ++kt) {
                    int key = kt * 16 + l15;
#pragma unroll
                    for (int r = 0; r < 4; ++r) {
                        int qr = wave * 16 + g * 4 + r;
                        if (key > qr) s[kt][r] = -INFINITY;
                    }
                }
            }
            float mt[4];
#pragma unroll
            for (int r = 0; r < 4; ++r) {
                mt[r] = fmaxf(fmaxf(s[0][r], s[1][r]), fmaxf(s[2][r], s[3][r]));
                mt[r] = fmaxf(mt[r], __shfl_xor(mt[r], 1));
                mt[r] = fmaxf(mt[r], __shfl_xor(mt[r], 2));
                mt[r] = fmaxf(mt[r], __shfl_xor(mt[r], 4));
                mt[r] = fmaxf(mt[r], __shfl_xor(mt[r], 8));
            }
            // defer-max (T13): rescale only when a row's max grew > 8
            bool need = false;
#pragma unroll
            for (int r = 0; r < 4; ++r) need |= (mt[r] > m_run[r] + 8.f);
            if (__any((int)need)) {
#pragma unroll
                for (int r = 0; r < 4; ++r) {
                    float mnew = fmaxf(m_run[r], mt[r]);
                    float a = __expf(m_run[r] - mnew);
                    m_run[r] = mnew;
                    l_run[r] *= a;
                    o[0][r] *= a; o[1][r] *= a; o[2][r] *= a; o[3][r] *= a;
                }
            }
            float ls[4];
#pragma unroll
            for (int r = 0; r < 4; ++r) {
                float sum = 0.f;
#pragma unroll
                for (int kt = 0; kt < 4; ++kt) {
                    float p = __expf(s[kt][r] - m_run[r]);
                    s[kt][r] = p;
                    sum += p;
                }
                ls[r] = sum;
            }
#pragma unroll
            for (int r = 0; r < 4; ++r) {
                ls[r] += __shfl_xor(ls[r], 1);
                ls[r] += __shfl_xor(ls[r], 2);
                ls[r] += __shfl_xor(ls[r], 4);
                ls[r] += __shfl_xor(ls[r], 8);
                l_run[r] += ls[r];
            }
#pragma unroll
            for (int kt = 0; kt < 4; ++kt)
#pragma unroll
                for (int r = 0; r < 4; ++r)
                    PsF[wave][PSZ(g * 4 + r, kt * 16 + l15)] = f2bf_fast(s[kt][r]);
            // O += P V
#pragma unroll
            for (int c = 0; c < 2; ++c) {
                bf16x8 ap = *(const bf16x8*)&PsF[wave][PSZ(l15, c * 32 + g * 8)];
#pragma unroll
                for (int dt = 0; dt < 4; ++dt) {
                    bf16x8 bv = *(const bf16x8*)&VtF[cur][SWZ(dt * 16 + l15, c * 32 + g * 8)];
                    o[dt] = __builtin_amdgcn_mfma_f32_16x16x32_bf16(ap, bv, o[dt], 0, 0, 0);
                }
            }
            if (pf) {
                *(u16x8*)&KsF[cur ^ 1][SWZ(rS, cS)] = pk0;
                *(u16x8*)&KsF[cur ^ 1][SWZ(32 + rS, cS)] = pk1;
#pragma unroll
                for (int j = 0; j < 8; ++j) {
                    VtF[cur ^ 1][SWZ(cS + j, rS)] = pv0[j];
                    VtF[cur ^ 1][SWZ(cS + j, 32 + rS)] = pv1[j];
                }
                __syncthreads();
            }
        }
        float inv[4];
#pragma unroll
        for (int r = 0; r < 4; ++r) inv[r] = 1.f / l_run[r];
#pragma unroll
        for (int dt = 0; dt < 4; ++dt)
#pragma unroll
            for (int r = 0; r < 4; ++r) {
                int row = qt * 64 + wave * 16 + g * 4 + r;
                cat[((size_t)b * Tt + row) * (Hh * 64) + h * 64 + dt * 16 + l15] =
                    f2bf_fast(o[dt][r] * inv[r]);
            }
    }
}

// -------------------- K3: proj (MFMA) + residual + LN1 -> h1, h1b ----------
__global__ __launch_bounds__(256) void proj_ln1_mfma(
    const uint16_t* __restrict__ cat, const uint16_t* __restrict__ WptS,
    const float* __restrict__ bp, const float* __restrict__ x,
    const float* __restrict__ g1, const float* __restrict__ be1,
    float* __restrict__ h1, uint16_t* __restrict__ h1b)
{
    __shared__ uint16_t WptF[64 * 520];   // 66.6 KB
    const int rt = blockIdx.x;
    const int t = threadIdx.x, lane = t & 63, w = t >> 6;
    const int l15 = lane & 15, g = lane >> 4;
    {   // 33280 u16 = 4160 u16x8, pre-swizzled -> linear vector copy
        const u16x8* src = (const u16x8*)WptS;
        u16x8* dst = (u16x8*)WptF;
#pragma unroll
        for (int p = 0; p < 16; ++p) dst[p * 256 + t] = src[p * 256 + t];
        if (t < 64) dst[4096 + t] = src[4096 + t];
    }
    __syncthreads();
    const int arow = rt * 64 + w * 16 + l15;
    f32x4 acc[4] = {};
#pragma unroll
    for (int kt = 0; kt < 16; ++kt) {
        bf16x8 a = *(const bf16x8*)&cat[(size_t)arow * 512 + kt * 32 + g * 8];
#pragma unroll
        for (int ct = 0; ct < 4; ++ct) {
            bf16x8 bfr = *(const bf16x8*)&WptF[WPSWZ(ct * 16 + l15, kt * 32 + g * 8)];
            acc[ct] = __builtin_amdgcn_mfma_f32_16x16x32_bf16(a, bfr, acc[ct], 0, 0, 0);
        }
    }
    float bpv[4], g1v[4], b1v[4];
#pragma unroll
    for (int ct = 0; ct < 4; ++ct) {
        bpv[ct] = bp[ct * 16 + l15];
        g1v[ct] = g1[ct * 16 + l15];
        b1v[ct] = be1[ct * 16 + l15];
    }
#pragma unroll
    for (int rr = 0; rr < 4; ++rr) {
        int drow = rt * 64 + w * 16 + g * 4 + rr;
        float s[4], sum = 0.f;
#pragma unroll
        for (int ct = 0; ct < 4; ++ct) {
            s[ct] = acc[ct][rr] + bpv[ct] + x[(size_t)drow * 64 + ct * 16 + l15];
            sum += s[ct];
        }
        sum += __shfl_xor(sum, 1); sum += __shfl_xor(sum, 2);
        sum += __shfl_xor(sum, 4); sum += __shfl_xor(sum, 8);
        float mu = sum * (1.f / 64.f);
        float v = 0.f;
#pragma unroll
        for (int ct = 0; ct < 4; ++ct) { s[ct] -= mu; v += s[ct] * s[ct]; }
        v += __shfl_xor(v, 1); v += __shfl_xor(v, 2);
        v += __shfl_xor(v, 4); v += __shfl_xor(v, 8);
        float rstd = rsqrtf(v * (1.f / 64.f) + 1e-5f);
#pragma unroll
        for (int ct = 0; ct < 4; ++ct) {
            float hv = s[ct] * rstd * g1v[ct] + b1v[ct];
            h1 [(size_t)drow * 64 + ct * 16 + l15] = hv;
            h1b[(size_t)drow * 64 + ct * 16 + l15] = f2bf_fast(hv);
        }
    }
}

// -------------------- K4: FFN (MFMA x2) + residual + LN2 -> out ------------
__global__ __launch_bounds__(256) void ffn_mfma(
    const uint16_t* __restrict__ h1b, const float* __restrict__ h1,
    const uint16_t* __restrict__ w1g, const float* __restrict__ b1,
    const uint16_t* __restrict__ w2g, const float* __restrict__ b2,
    const float* __restrict__ g2, const float* __restrict__ be2,
    float* __restrict__ out)
{
    __shared__ uint16_t W1s[256 * 72];       // 36 KB  [col<256][k<64]
    __shared__ uint16_t W2s[64 * 264];       // 33.8 KB [col<64][k<256]
    __shared__ uint16_t hidS[4][16 * 264];   // 33.8 KB wave-private [q][k]
    const int rt = blockIdx.x;
    const int t = threadIdx.x, lane = t & 63, w = t >> 6;
    const int l15 = lane & 15, g = lane >> 4;
    {   // W1s: 18432 u16 = 2304 u16x8 (9 iters exact); W2s: 16896 = 2112 (8 + 64)
        const u16x8* s1 = (const u16x8*)w1g;
        u16x8* d1 = (u16x8*)W1s;
#pragma unroll
        for (int p = 0; p < 9; ++p) d1[p * 256 + t] = s1[p * 256 + t];
        const u16x8* s2 = (const u16x8*)w2g;
        u16x8* d2 = (u16x8*)W2s;
#pragma unroll
        for (int p = 0; p < 8; ++p) d2[p * 256 + t] = s2[p * 256 + t];
        if (t < 64) d2[2048 + t] = s2[2048 + t];
    }
    __syncthreads();
    const int arow = rt * 64 + w * 16 + l15;
    // phase 1: hid[16 rows][256] = relu(h1b @ W1 + b1)
    f32x4 acc1[16] = {};
#pragma unroll
    for (int ks = 0; ks < 2; ++ks) {
        bf16x8 a = *(const bf16x8*)&h1b[(size_t)arow * 64 + ks * 32 + g * 8];
#pragma unroll
        for (int ct = 0; ct < 16; ++ct) {
            bf16x8 bfr = *(const bf16x8*)&W1s[SWZ(ct * 16 + l15, ks * 32 + g * 8)];
            acc1[ct] = __builtin_amdgcn_mfma_f32_16x16x32_bf16(a, bfr, acc1[ct], 0, 0, 0);
        }
    }
#pragma unroll
    for (int ct = 0; ct < 16; ++ct) {
        float bb = b1[ct * 16 + l15];
#pragma unroll
        for (int rr = 0; rr < 4; ++rr)
            hidS[w][(g * 4 + rr) * 264 + ct * 16 + l15] =
                f2bf_fast(fmaxf(acc1[ct][rr] + bb, 0.f));
    }
    // phase 2: out16x64 = hid @ W2 (same-wave LDS write->read)
    f32x4 acc2[4] = {};
#pragma unroll
    for (int ks = 0; ks < 8; ++ks) {
        bf16x8 a = *(const bf16x8*)&hidS[w][l15 * 264 + ks * 32 + g * 8];
#pragma unroll
        for (int ct = 0; ct < 4; ++ct) {
            bf16x8 bfr = *(const bf16x8*)&W2s[W2SWZ(ct * 16 + l15, ks * 32 + g * 8)];
            acc2[ct] = __builtin_amdgcn_mfma_f32_16x16x32_bf16(a, bfr, acc2[ct], 0, 0, 0);
        }
    }
    float b2v[4], g2v[4], be2v[4];
#pragma unroll
    for (int ct = 0; ct < 4; ++ct) {
        b2v[ct]  = b2[ct * 16 + l15];
        g2v[ct]  = g2[ct * 16 + l15];
        be2v[ct] = be2[ct * 16 + l15];
    }
#pragma unroll
    for (int rr = 0; rr < 4; ++rr) {
        int drow = rt * 64 + w * 16 + g * 4 + rr;
        float s[4], sum = 0.f;
#pragma unroll
        for (int ct = 0; ct < 4; ++ct) {
            s[ct] = acc2[ct][rr] + b2v[ct] + h1[(size_t)drow * 64 + ct * 16 + l15];
            sum += s[ct];
        }
        sum += __shfl_xor(sum, 1); sum += __shfl_xor(sum, 2);
        sum += __shfl_xor(sum, 4); sum += __shfl_xor(sum, 8);
        float mu = sum * (1.f / 64.f);
        float v = 0.f;
#pragma unroll
        for (int ct = 0; ct < 4; ++ct) { s[ct] -= mu; v += s[ct] * s[ct]; }
        v += __shfl_xor(v, 1); v += __shfl_xor(v, 2);
        v += __shfl_xor(v, 4); v += __shfl_xor(v, 8);
        float rstd = rsqrtf(v * (1.f / 64.f) + 1e-5f);
#pragma unroll
        for (int ct = 0; ct < 4; ++ct)
            out[(size_t)drow * 64 + ct * 16 + l15] =
                s[ct] * rstd * g2v[ct] + be2v[ct];
    }
}

// ---------------------------------------------------------------------------
extern "C" void kernel_launch(void* const* d_in, const int* in_sizes, int n_in,
                              void* d_out, int out_size, void* d_ws, size_t ws_size,
                              hipStream_t stream)
{
    (void)in_sizes; (void)n_in; (void)out_size; (void)ws_size;
    const float* x   = (const float*)d_in[0];
    const float* Wq  = (const float*)d_in[1];
    const float* bq  = (const float*)d_in[2];
    const float* Wk  = (const float*)d_in[3];
    const float* bk  = (const float*)d_in[4];
    const float* Wv  = (const float*)d_in[5];
    const float* bv  = (const float*)d_in[6];
    const float* Wp  = (const float*)d_in[7];
    const float* bp  = (const float*)d_in[8];
    const float* W1  = (const float*)d_in[9];
    const float* b1  = (const float*)d_in[10];
    const float* W2  = (const float*)d_in[11];
    const float* b2  = (const float*)d_in[12];
    const float* g1  = (const float*)d_in[13];
    const float* be1 = (const float*)d_in[14];
    const float* g2  = (const float*)d_in[15];
    const float* be2 = (const float*)d_in[16];
    float* outp = (float*)d_out;

    char* w = (char*)d_ws;
    uint16_t* qb   = (uint16_t*)w;                      // [H][NT][64] 8MB
    uint16_t* kb   = qb + (size_t)Hh * NT * 64;         // 8MB
    uint16_t* vb   = kb + (size_t)Hh * NT * 64;         // 8MB
    uint16_t* cat  = vb + (size_t)Hh * NT * 64;         // [NT][512] 8MB
    float*    h1   = (float*)(cat + (size_t)NT * 512);  // [NT][64] fp32 2MB
    uint16_t* h1b  = (uint16_t*)(h1 + (size_t)NT * 64); // [NT][64] 1MB
    uint16_t* xb   = h1b + (size_t)NT * 64;             // [NT][64] 1MB
    uint16_t* WtAll= xb + (size_t)NT * 64;              // 24*4608 u16
    uint16_t* WptS = WtAll + (size_t)24 * 4608;         // 33280 u16
    uint16_t* W1g  = WptS + 33280;                      // 18432 u16
    uint16_t* W2g  = W1g + 18432;                       // 16896 u16

    setup_kernel<<<dim3(296), dim3(256), 0, stream>>>(
        x, Wq, Wk, Wv, Wp, W1, W2, xb, WtAll, WptS, W1g, W2g);
    qkv_kernel<<<dim3(NT / 64, Hh, 3), dim3(256), 0, stream>>>(
        xb, WtAll, bq, bk, bv, qb, kb, vb);
    attn_kernel4<<<dim3(512), dim3(256), 0, stream>>>(qb, kb, vb, cat);
    proj_ln1_mfma<<<dim3(NT / 64), dim3(256), 0, stream>>>(
        cat, WptS, bp, x, g1, be1, h1, h1b);
    ffn_mfma<<<dim3(NT / 64), dim3(256), 0, stream>>>(
        h1b, h1, W1g, b1, W2g, b2, g2, be2, outp);
}

// Round 7
// 175.244 us; speedup vs baseline: 1.9279x; 1.0573x over previous
//
#include <hip/hip_runtime.h>
#include <hip/hip_bf16.h>
#include <stdint.h>

#define Dd 64
#define Hh 8
#define Bb 4
#define Tt 2048
#define NT (Bb * Tt)   // 8192 token rows

typedef __attribute__((ext_vector_type(4))) float f32x4;
typedef __attribute__((ext_vector_type(8))) __bf16 bf16x8;
typedef __attribute__((ext_vector_type(8))) uint16_t u16x8;
typedef __attribute__((ext_vector_type(4))) uint16_t u16x4;

__device__ __forceinline__ uint16_t f2bf_fast(float f) {
    union { __bf16 h; uint16_t u; } c; c.h = (__bf16)f; return c.u;
}
// pack two fp32 -> one u32 of 2 bf16 (lo=a, hi=b)
__device__ __forceinline__ uint32_t pkbf(float a, float b) {
    return (uint32_t)f2bf_fast(a) | ((uint32_t)f2bf_fast(b) << 16);
}

// XOR-swizzled layouts (see earlier rounds). Same math used for the setup
// kernel's pre-swizzled global weight copies and the in-kernel reads.
#define SWZ(row, k)   ((row) * 72  + ((k) ^ ((((row) >> 3) & 7) << 3)))   // k<64
#define PSZ(q, k)     ((q)  * 72  + ((k) ^ ((((q)  >> 2) & 3) << 3)))    // 16 q
#define HSZ(q, k)     ((q)  * 264 + ((k) ^ ((((q)  >> 2) & 3) << 3)))    // k<256
#define W2SWZ(col, k) ((col) * 264 + ((k) ^ ((((col) >> 3) & 7) << 3)))  // k<256
#define WPSWZ(col, k) ((col) * 520 + ((k) ^ ((((col) >> 3) & 7) << 3)))  // k<512

// -------------------- K0: weight pre-swizzle (16 blocks) -------------------
// bid 0-7: Wp -> WptS ; 8-11: W1 -> W1g ; 12-15: W2 -> W2g
__global__ __launch_bounds__(256) void setup_kernel(
    const float* __restrict__ Wp, const float* __restrict__ W1,
    const float* __restrict__ W2,
    uint16_t* __restrict__ WptS, uint16_t* __restrict__ W1g,
    uint16_t* __restrict__ W2g)
{
    const int bid = blockIdx.x, t = threadIdx.x;
    if (bid < 8) {
        const int j = bid;                 // k-chunk of 64
#pragma unroll
        for (int p = 0; p < 16; ++p) {
            int idx = p * 256 + t;
            int col = idx & 63, k = j * 64 + (idx >> 6);
            WptS[WPSWZ(col, k)] = f2bf_fast(Wp[(size_t)k * 64 + col]);
        }
    } else if (bid < 12) {
        const int j = bid - 8;
#pragma unroll
        for (int p = 0; p < 16; ++p) {
            int e = j * 4096 + p * 256 + t;
            int col = e & 255, k = e >> 8;
            W1g[SWZ(col, k)] = f2bf_fast(W1[(size_t)k * 256 + col]);
        }
    } else {
        const int j = bid - 12;
#pragma unroll
        for (int p = 0; p < 16; ++p) {
            int e = j * 4096 + p * 256 + t;
            int col = e & 63, k = e >> 6;
            W2g[W2SWZ(col, k)] = f2bf_fast(W2[(size_t)k * 64 + col]);
        }
    }
}

// -------------------- K1: per-head QKV projections (bf16 MFMA) -------------
// grid (128 row-tiles, H, 3 mats), block 256 (4 waves). Self-contained
// (converts fp32 x / W in-kernel; round-5-verified structure).
__global__ __launch_bounds__(256) void qkv_kernel(
    const float* __restrict__ x,
    const float* __restrict__ Wq, const float* __restrict__ bq,
    const float* __restrict__ Wk, const float* __restrict__ bk,
    const float* __restrict__ Wv, const float* __restrict__ bv,
    uint16_t* __restrict__ qb, uint16_t* __restrict__ kb, uint16_t* __restrict__ vb)
{
    __shared__ uint16_t WtF[64 * 72];   // W^T bf16 swizzled: (out, in)
    const int rt = blockIdx.x, h = blockIdx.y, m = blockIdx.z;
    const float* W    = (m == 0) ? Wq : (m == 1) ? Wk : Wv;
    const float* bias = (m == 0) ? bq : (m == 1) ? bk : bv;
    uint16_t*    out  = (m == 0) ? qb : (m == 1) ? kb : vb;
    const int t = threadIdx.x, lane = t & 63, w = t >> 6;
    const int l15 = lane & 15, g = lane >> 4;

#pragma unroll
    for (int p = 0; p < 4; ++p) {
        int idx = p * 256 + t;
        int r = idx >> 4, c4 = (idx & 15) * 4;
        f32x4 wv = *(const f32x4*)&W[(size_t)(h * 64 + r) * 64 + c4];
#pragma unroll
        for (int j = 0; j < 4; ++j) WtF[SWZ(c4 + j, r)] = f2bf_fast(wv[j]);
    }
    const int row = rt * 64 + w * 16 + l15;
    union { u16x8 u; bf16x8 b; } a0, a1;
    {
        f32x4 x0 = *(const f32x4*)&x[(size_t)row * 64 + g * 8];
        f32x4 x1 = *(const f32x4*)&x[(size_t)row * 64 + g * 8 + 4];
        f32x4 x2 = *(const f32x4*)&x[(size_t)row * 64 + 32 + g * 8];
        f32x4 x3 = *(const f32x4*)&x[(size_t)row * 64 + 32 + g * 8 + 4];
#pragma unroll
        for (int j = 0; j < 4; ++j) {
            a0.u[j] = f2bf_fast(x0[j]); a0.u[4 + j] = f2bf_fast(x1[j]);
            a1.u[j] = f2bf_fast(x2[j]); a1.u[4 + j] = f2bf_fast(x3[j]);
        }
    }
    __syncthreads();

    f32x4 acc[4] = {};
#pragma unroll
    for (int ct = 0; ct < 4; ++ct) {
        bf16x8 b0 = *(const bf16x8*)&WtF[SWZ(ct * 16 + l15, g * 8)];
        bf16x8 b1 = *(const bf16x8*)&WtF[SWZ(ct * 16 + l15, 32 + g * 8)];
        acc[ct] = __builtin_amdgcn_mfma_f32_16x16x32_bf16(a0.b, b0, acc[ct], 0, 0, 0);
        acc[ct] = __builtin_amdgcn_mfma_f32_16x16x32_bf16(a1.b, b1, acc[ct], 0, 0, 0);
    }
#pragma unroll
    for (int ct = 0; ct < 4; ++ct) {
        float bb = bias[h * 64 + ct * 16 + l15];
#pragma unroll
        for (int rr = 0; rr < 4; ++rr) {
            int orow = rt * 64 + w * 16 + g * 4 + rr;
            out[((size_t)h * NT + orow) * 64 + ct * 16 + l15] =
                f2bf_fast(acc[ct][rr] + bb);
        }
    }
}

// -------------------- K2: flash attention, swapped QK^T + in-register P ----
// 1024 blocks x 128 threads (2 waves x 16 q-rows = 32-row q-tiles).
// Pairing: block handles q-tiles {p, 63-p} -> constant 33 kv-iters.
// Swapped QK^T (mfma(K,Q)) puts each q-row's P in ONE lane; the sigma
// slot-permutation (applied to BOTH P-A-frag and V-B-frag) makes the PV
// A-fragment the lane's own packed registers: no P LDS, no shuffles.
__global__ __launch_bounds__(128) void attn_kernel5(
    const uint16_t* __restrict__ qb, const uint16_t* __restrict__ kb,
    const uint16_t* __restrict__ vb, uint16_t* __restrict__ cat)
{
    __shared__ uint16_t KsF[2][64 * 72];   // K row-major [key][d], swizzled
    __shared__ uint16_t VtF[2][64 * 72];   // V transposed [d][key], swizzled
    const int bid = blockIdx.x;
    const int lbid = (bid & 7) * 128 + (bid >> 3);   // XCD swizzle, 1024%8==0
    const int pairid = lbid & 31;
    const int hb = lbid >> 5;
    const int h = hb & 7, b = hb >> 3;
    const int t = threadIdx.x, lane = t & 63, w = t >> 6;   // w in {0,1}
    const int l15 = lane & 15, g = lane >> 4;
    const size_t base = ((size_t)h * NT + (size_t)b * Tt) * 64;
    const uint16_t* Qh = qb + base;
    const uint16_t* Kh = kb + base;
    const uint16_t* Vh = vb + base;

    for (int ph = 0; ph < 2; ++ph) {
        const int qt32 = ph ? (63 - pairid) : pairid;
        // Q as B-fragment: col=q=l15 (within wave's 16 rows), k=d=g*8+e
        bf16x8 aq0, aq1;
        {
            int qrow = qt32 * 32 + w * 16 + l15;
            aq0 = *(const bf16x8*)&Qh[(size_t)qrow * 64 + g * 8];
            aq1 = *(const bf16x8*)&Qh[(size_t)qrow * 64 + 32 + g * 8];
        }
        f32x4 o[4] = {};                  // O[q=g*4+rj][d=dt*16+l15]
        float m_run = -INFINITY, l_run = 0.f;   // per-lane: q = l15

        __syncthreads();                  // protect buf0 from previous phase
        // prologue: stage kv=0 into buffer 0
#pragma unroll
        for (int i = 0; i < 4; ++i) {
            int slot = i * 128 + t;
            int r = slot >> 3, c8 = (slot & 7) * 8;
            u16x8 kk = *(const u16x8*)&Kh[(size_t)r * 64 + c8];
            u16x8 vv = *(const u16x8*)&Vh[(size_t)r * 64 + c8];
            *(u16x8*)&KsF[0][SWZ(r, c8)] = kk;
#pragma unroll
            for (int j = 0; j < 8; ++j) VtF[0][SWZ(c8 + j, r)] = vv[j];
        }
        __syncthreads();

        const int nkv = (qt32 >> 1) + 1;
        for (int kv = 0; kv < nkv; ++kv) {
            const int cur = kv & 1;
            const bool pf = (kv + 1) < nkv;
            u16x8 pK[4], pV[4];
            if (pf) {
#pragma unroll
                for (int i = 0; i < 4; ++i) {
                    int slot = i * 128 + t;
                    int r = (kv + 1) * 64 + (slot >> 3), c8 = (slot & 7) * 8;
                    pK[i] = *(const u16x8*)&Kh[(size_t)r * 64 + c8];
                    pV[i] = *(const u16x8*)&Vh[(size_t)r * 64 + c8];
                }
            }
            // S^T = K Q : s[kt][rj] = S[key=kt*16+g*4+rj][q=l15]
            f32x4 s[4];
#pragma unroll
            for (int kt = 0; kt < 4; ++kt) {
                bf16x8 bk0 = *(const bf16x8*)&KsF[cur][SWZ(kt * 16 + l15, g * 8)];
                bf16x8 bk1 = *(const bf16x8*)&KsF[cur][SWZ(kt * 16 + l15, 32 + g * 8)];
                f32x4 z = {};
                z = __builtin_amdgcn_mfma_f32_16x16x32_bf16(bk0, aq0, z, 0, 0, 0);
                z = __builtin_amdgcn_mfma_f32_16x16x32_bf16(bk1, aq1, z, 0, 0, 0);
                s[kt] = z;
            }
            if (kv == nkv - 1) {   // diagonal tile: mask key > q
                int qlocal = (qt32 & 1) * 32 + w * 16 + l15;
#pragma unroll
                for (int kt = 0; kt < 4; ++kt)
#pragma unroll
                    for (int rj = 0; rj < 4; ++rj)
                        if (kt * 16 + g * 4 + rj > qlocal) s[kt][rj] = -INFINITY;
            }
            // row max for q=l15 (16 in-lane values + 4 g-replicas)
            float mt = s[0][0];
#pragma unroll
            for (int kt = 0; kt < 4; ++kt)
#pragma unroll
                for (int rj = 0; rj < 4; ++rj) mt = fmaxf(mt, s[kt][rj]);
            mt = fmaxf(mt, __shfl_xor(mt, 16));
            mt = fmaxf(mt, __shfl_xor(mt, 32));
            // defer-max (T13)
            if (__any((int)(mt > m_run + 8.f))) {
                float mnew = fmaxf(m_run, mt);
                float alpha = __expf(m_run - mnew);
                m_run = mnew;
                l_run *= alpha;
                float a0 = __shfl(alpha, g * 4 + 0);
                float a1 = __shfl(alpha, g * 4 + 1);
                float a2 = __shfl(alpha, g * 4 + 2);
                float a3 = __shfl(alpha, g * 4 + 3);
#pragma unroll
                for (int dt = 0; dt < 4; ++dt) {
                    o[dt][0] *= a0; o[dt][1] *= a1; o[dt][2] *= a2; o[dt][3] *= a3;
                }
            }
            // exp + row sum
            float ls = 0.f;
#pragma unroll
            for (int kt = 0; kt < 4; ++kt)
#pragma unroll
                for (int rj = 0; rj < 4; ++rj) {
                    float p = __expf(s[kt][rj] - m_run);
                    s[kt][rj] = p;
                    ls += p;
                }
            ls += __shfl_xor(ls, 16);
            ls += __shfl_xor(ls, 32);
            l_run += ls;
            // pack P: lane's own values, sigma-ordered A-fragments
            union { uint32_t wd[4]; bf16x8 v; } ap0, ap1;
            ap0.wd[0] = pkbf(s[0][0], s[0][1]); ap0.wd[1] = pkbf(s[0][2], s[0][3]);
            ap0.wd[2] = pkbf(s[1][0], s[1][1]); ap0.wd[3] = pkbf(s[1][2], s[1][3]);
            ap1.wd[0] = pkbf(s[2][0], s[2][1]); ap1.wd[1] = pkbf(s[2][2], s[2][3]);
            ap1.wd[2] = pkbf(s[3][0], s[3][1]); ap1.wd[3] = pkbf(s[3][2], s[3][3]);
            // O += P V  (B-frag reads sigma-permuted: two b64 per fragment)
#pragma unroll
            for (int c = 0; c < 2; ++c) {
                const bf16x8 ap = c ? ap1.v : ap0.v;
#pragma unroll
                for (int dt = 0; dt < 4; ++dt) {
                    union { u16x4 q[2]; bf16x8 v; } bb;
                    bb.q[0] = *(const u16x4*)&VtF[cur][SWZ(dt * 16 + l15, c * 32 + g * 4)];
                    bb.q[1] = *(const u16x4*)&VtF[cur][SWZ(dt * 16 + l15, c * 32 + 16 + g * 4)];
                    o[dt] = __builtin_amdgcn_mfma_f32_16x16x32_bf16(ap, bb.v, o[dt], 0, 0, 0);
                }
            }
            if (pf) {
#pragma unroll
                for (int i = 0; i < 4; ++i) {
                    int slot = i * 128 + t;
                    int r = slot >> 3, c8 = (slot & 7) * 8;
                    *(u16x8*)&KsF[cur ^ 1][SWZ(r, c8)] = pK[i];
#pragma unroll
                    for (int j = 0; j < 8; ++j) VtF[cur ^ 1][SWZ(c8 + j, r)] = pV[i][j];
                }
                __syncthreads();
            }
        }
        // epilogue
        float inv = 1.f / l_run;
        float i0 = __shfl(inv, g * 4 + 0);
        float i1 = __shfl(inv, g * 4 + 1);
        float i2 = __shfl(inv, g * 4 + 2);
        float i3 = __shfl(inv, g * 4 + 3);
#pragma unroll
        for (int dt = 0; dt < 4; ++dt) {
            int rowb = qt32 * 32 + w * 16 + g * 4;
            size_t cb = ((size_t)b * Tt + rowb) * 512 + h * 64 + dt * 16 + l15;
            cat[cb]         = f2bf_fast(o[dt][0] * i0);
            cat[cb + 512]   = f2bf_fast(o[dt][1] * i1);
            cat[cb + 1024]  = f2bf_fast(o[dt][2] * i2);
            cat[cb + 1536]  = f2bf_fast(o[dt][3] * i3);
        }
    }
}

// -------------------- K3: fused proj+LN1+FFN+LN2 -> out --------------------
// 256 blocks x 128 threads (2 waves x 16 rows). Weights read as B-fragments
// directly from pre-swizzled global (L2-resident). No __syncthreads at all:
// h1/hid transposes via wave-private LDS (same-wave write->read).
__global__ __launch_bounds__(128) void tail_kernel(
    const uint16_t* __restrict__ cat, const uint16_t* __restrict__ WptS,
    const uint16_t* __restrict__ W1g, const uint16_t* __restrict__ W2g,
    const float* __restrict__ bp, const float* __restrict__ b1,
    const float* __restrict__ b2, const float* __restrict__ x,
    const float* __restrict__ g1, const float* __restrict__ be1,
    const float* __restrict__ g2, const float* __restrict__ be2,
    float* __restrict__ out)
{
    __shared__ uint16_t h1S[2][16 * 72];     // per-wave h1 transpose stage
    __shared__ uint16_t hidS[2][16 * 264];   // per-wave hidden transpose stage
    const int rt = blockIdx.x;
    const int t = threadIdx.x, lane = t & 63, w = t >> 6;
    const int l15 = lane & 15, g = lane >> 4;
    const int arow = rt * 32 + w * 16 + l15;

    // ---- proj: cat[32 rows x 512] @ Wp[512 x 64]
    f32x4 acc[4] = {};
#pragma unroll
    for (int kt = 0; kt < 16; ++kt) {
        bf16x8 a = *(const bf16x8*)&cat[(size_t)arow * 512 + kt * 32 + g * 8];
#pragma unroll
        for (int ct = 0; ct < 4; ++ct) {
            bf16x8 bfr = *(const bf16x8*)&WptS[WPSWZ(ct * 16 + l15, kt * 32 + g * 8)];
            acc[ct] = __builtin_amdgcn_mfma_f32_16x16x32_bf16(a, bfr, acc[ct], 0, 0, 0);
        }
    }
    // ---- bias + residual + LN1 ; keep h1 in regs (C layout) + stage for A-frags
    float bpv[4], g1v[4], b1v[4];
#pragma unroll
    for (int ct = 0; ct < 4; ++ct) {
        bpv[ct] = bp[ct * 16 + l15];
        g1v[ct] = g1[ct * 16 + l15];
        b1v[ct] = be1[ct * 16 + l15];
    }
    float hv[4][4];   // [ct][rr] = h1[q=g*4+rr][d=ct*16+l15]
#pragma unroll
    for (int rr = 0; rr < 4; ++rr) {
        int drow = rt * 32 + w * 16 + g * 4 + rr;
        float s[4], sum = 0.f;
#pragma unroll
        for (int ct = 0; ct < 4; ++ct) {
            s[ct] = acc[ct][rr] + bpv[ct] + x[(size_t)drow * 64 + ct * 16 + l15];
            sum += s[ct];
        }
        sum += __shfl_xor(sum, 1); sum += __shfl_xor(sum, 2);
        sum += __shfl_xor(sum, 4); sum += __shfl_xor(sum, 8);
        float mu = sum * (1.f / 64.f);
        float v = 0.f;
#pragma unroll
        for (int ct = 0; ct < 4; ++ct) { s[ct] -= mu; v += s[ct] * s[ct]; }
        v += __shfl_xor(v, 1); v += __shfl_xor(v, 2);
        v += __shfl_xor(v, 4); v += __shfl_xor(v, 8);
        float rstd = rsqrtf(v * (1.f / 64.f) + 1e-5f);
#pragma unroll
        for (int ct = 0; ct < 4; ++ct) {
            float h = s[ct] * rstd * g1v[ct] + b1v[ct];
            hv[ct][rr] = h;
            h1S[w][PSZ(g * 4 + rr, ct * 16 + l15)] = f2bf_fast(h);
        }
    }
    // ---- ffn1: hid = relu(h1 @ W1 + b1), staged transposed for ffn2 A-frags
    bf16x8 ha0 = *(const bf16x8*)&h1S[w][PSZ(l15, g * 8)];
    bf16x8 ha1 = *(const bf16x8*)&h1S[w][PSZ(l15, 32 + g * 8)];
#pragma unroll
    for (int nt = 0; nt < 16; ++nt) {
        f32x4 a1c = {};
        bf16x8 w10 = *(const bf16x8*)&W1g[SWZ(nt * 16 + l15, g * 8)];
        bf16x8 w11 = *(const bf16x8*)&W1g[SWZ(nt * 16 + l15, 32 + g * 8)];
        a1c = __builtin_amdgcn_mfma_f32_16x16x32_bf16(ha0, w10, a1c, 0, 0, 0);
        a1c = __builtin_amdgcn_mfma_f32_16x16x32_bf16(ha1, w11, a1c, 0, 0, 0);
        float bb1 = b1[nt * 16 + l15];
#pragma unroll
        for (int rr = 0; rr < 4; ++rr)
            hidS[w][HSZ(g * 4 + rr, nt * 16 + l15)] =
                f2bf_fast(fmaxf(a1c[rr] + bb1, 0.f));
    }
    // ---- ffn2: out32x64 = hid @ W2
    f32x4 acc2[4] = {};
#pragma unroll
    for (int ks = 0; ks < 8; ++ks) {
        bf16x8 hfr = *(const bf16x8*)&hidS[w][HSZ(l15, ks * 32 + g * 8)];
#pragma unroll
        for (int ct = 0; ct < 4; ++ct) {
            bf16x8 w2f = *(const bf16x8*)&W2g[W2SWZ(ct * 16 + l15, ks * 32 + g * 8)];
            acc2[ct] = __builtin_amdgcn_mfma_f32_16x16x32_bf16(hfr, w2f, acc2[ct], 0, 0, 0);
        }
    }
    // ---- + b2 + residual(h1 regs) + LN2 -> out
    float b2v[4], g2v[4], be2v[4];
#pragma unroll
    for (int ct = 0; ct < 4; ++ct) {
        b2v[ct]  = b2[ct * 16 + l15];
        g2v[ct]  = g2[ct * 16 + l15];
        be2v[ct] = be2[ct * 16 + l15];
    }
#pragma unroll
    for (int rr = 0; rr < 4; ++rr) {
        int drow = rt * 32 + w * 16 + g * 4 + rr;
        float s[4], sum = 0.f;
#pragma unroll
        for (int ct = 0; ct < 4; ++ct) {
            s[ct] = acc2[ct][rr] + b2v[ct] + hv[ct][rr];
            sum += s[ct];
        }
        sum += __shfl_xor(sum, 1); sum += __shfl_xor(sum, 2);
        sum += __shfl_xor(sum, 4); sum += __shfl_xor(sum, 8);
        float mu = sum * (1.f / 64.f);
        float v = 0.f;
#pragma unroll
        for (int ct = 0; ct < 4; ++ct) { s[ct] -= mu; v += s[ct] * s[ct]; }
        v += __shfl_xor(v, 1); v += __shfl_xor(v, 2);
        v += __shfl_xor(v, 4); v += __shfl_xor(v, 8);
        float rstd = rsqrtf(v * (1.f / 64.f) + 1e-5f);
#pragma unroll
        for (int ct = 0; ct < 4; ++ct)
            out[(size_t)drow * 64 + ct * 16 + l15] =
                s[ct] * rstd * g2v[ct] + be2v[ct];
    }
}

// ---------------------------------------------------------------------------
extern "C" void kernel_launch(void* const* d_in, const int* in_sizes, int n_in,
                              void* d_out, int out_size, void* d_ws, size_t ws_size,
                              hipStream_t stream)
{
    (void)in_sizes; (void)n_in; (void)out_size; (void)ws_size;
    const float* x   = (const float*)d_in[0];
    const float* Wq  = (const float*)d_in[1];
    const float* bq  = (const float*)d_in[2];
    const float* Wk  = (const float*)d_in[3];
    const float* bk  = (const float*)d_in[4];
    const float* Wv  = (const float*)d_in[5];
    const float* bv  = (const float*)d_in[6];
    const float* Wp  = (const float*)d_in[7];
    const float* bp  = (const float*)d_in[8];
    const float* W1  = (const float*)d_in[9];
    const float* b1  = (const float*)d_in[10];
    const float* W2  = (const float*)d_in[11];
    const float* b2  = (const float*)d_in[12];
    const float* g1  = (const float*)d_in[13];
    const float* be1 = (const float*)d_in[14];
    const float* g2  = (const float*)d_in[15];
    const float* be2 = (const float*)d_in[16];
    float* outp = (float*)d_out;

    char* w = (char*)d_ws;
    uint16_t* qb   = (uint16_t*)w;                      // [H][NT][64] 8MB
    uint16_t* kb   = qb + (size_t)Hh * NT * 64;         // 8MB
    uint16_t* vb   = kb + (size_t)Hh * NT * 64;         // 8MB
    uint16_t* cat  = vb + (size_t)Hh * NT * 64;         // [NT][512] 8MB
    uint16_t* WptS = cat + (size_t)NT * 512;            // 33280 u16
    uint16_t* W1g  = WptS + 33280;                      // 18432 u16
    uint16_t* W2g  = W1g + 18432;                       // 16896 u16

    setup_kernel<<<dim3(16), dim3(256), 0, stream>>>(Wp, W1, W2, WptS, W1g, W2g);
    qkv_kernel<<<dim3(NT / 64, Hh, 3), dim3(256), 0, stream>>>(
        x, Wq, bq, Wk, bk, Wv, bv, qb, kb, vb);
    attn_kernel5<<<dim3(1024), dim3(128), 0, stream>>>(qb, kb, vb, cat);
    tail_kernel<<<dim3(256), dim3(128), 0, stream>>>(
        cat, WptS, W1g, W2g, bp, b1, b2, x, g1, be1, g2, be2, outp);
}

// Round 8
// 167.881 us; speedup vs baseline: 2.0125x; 1.0439x over previous
//
#include <hip/hip_runtime.h>
#include <hip/hip_bf16.h>
#include <stdint.h>

#define Dd 64
#define Hh 8
#define Bb 4
#define Tt 2048
#define NT (Bb * Tt)   // 8192 token rows

typedef __attribute__((ext_vector_type(4))) float f32x4;
typedef __attribute__((ext_vector_type(8))) __bf16 bf16x8;
typedef __attribute__((ext_vector_type(8))) uint16_t u16x8;
typedef __attribute__((ext_vector_type(4))) uint16_t u16x4;

__device__ __forceinline__ uint16_t f2bf_fast(float f) {
    union { __bf16 h; uint16_t u; } c; c.h = (__bf16)f; return c.u;
}
__device__ __forceinline__ uint32_t pkbf(float a, float b) {
    return (uint32_t)f2bf_fast(a) | ((uint32_t)f2bf_fast(b) << 16);
}

// XOR-swizzled layouts; same math for pre-swizzled global copies and reads.
#define SWZ(row, k)   ((row) * 72  + ((k) ^ ((((row) >> 3) & 7) << 3)))   // k<64
#define PSZ(q, k)     ((q)  * 72  + ((k) ^ ((((q)  >> 2) & 3) << 3)))    // 16 q
#define HSZ(q, k)     ((q)  * 264 + ((k) ^ ((((q)  >> 2) & 3) << 3)))    // k<256
#define W2SWZ(col, k) ((col) * 264 + ((k) ^ ((((col) >> 3) & 7) << 3)))  // k<256
#define WPSWZ(col, k) ((col) * 520 + ((k) ^ ((((col) >> 3) & 7) << 3)))  // k<512

// -------------------- K0: one-time conversions into workspace --------------
// [0,256): x->xb bf16 ; [256,280): Wqkv->WtAll (transposed+SWZ per (m,h)) ;
// [280,288): Wp->WptS ; [288,292): W1->W1g ; [292,296): W2->W2g
__global__ __launch_bounds__(256) void setup_kernel(
    const float* __restrict__ x,
    const float* __restrict__ Wq, const float* __restrict__ Wk,
    const float* __restrict__ Wv, const float* __restrict__ Wp,
    const float* __restrict__ W1, const float* __restrict__ W2,
    uint16_t* __restrict__ xb, uint16_t* __restrict__ WtAll,
    uint16_t* __restrict__ WptS, uint16_t* __restrict__ W1g,
    uint16_t* __restrict__ W2g)
{
    const int bid = blockIdx.x, t = threadIdx.x;
    if (bid < 256) {
        size_t base = ((size_t)bid * 256 + t) * 8;
        f32x4 a = *(const f32x4*)&x[base];
        f32x4 b = *(const f32x4*)&x[base + 4];
        u16x8 o;
#pragma unroll
        for (int j = 0; j < 4; ++j) { o[j] = f2bf_fast(a[j]); o[4 + j] = f2bf_fast(b[j]); }
        *(u16x8*)&xb[base] = o;
    } else if (bid < 280) {
        const int mh = bid - 256, m = mh / 8, h = mh % 8;
        const float* W = (m == 0) ? Wq : (m == 1) ? Wk : Wv;
        uint16_t* dst = WtAll + (size_t)mh * 4608;
#pragma unroll
        for (int p = 0; p < 4; ++p) {
            int idx = p * 256 + t;
            int k = idx >> 4, c4 = (idx & 15) * 4;
            f32x4 wv = *(const f32x4*)&W[(size_t)(h * 64 + k) * 64 + c4];
#pragma unroll
            for (int j = 0; j < 4; ++j) dst[SWZ(c4 + j, k)] = f2bf_fast(wv[j]);
        }
    } else if (bid < 288) {
        const int j = bid - 280;
#pragma unroll
        for (int p = 0; p < 16; ++p) {
            int idx = p * 256 + t;
            int col = idx & 63, k = j * 64 + (idx >> 6);
            WptS[WPSWZ(col, k)] = f2bf_fast(Wp[(size_t)k * 64 + col]);
        }
    } else if (bid < 292) {
        const int j = bid - 288;
#pragma unroll
        for (int p = 0; p < 16; ++p) {
            int e = j * 4096 + p * 256 + t;
            int col = e & 255, k = e >> 8;
            W1g[SWZ(col, k)] = f2bf_fast(W1[(size_t)k * 256 + col]);
        }
    } else {
        const int j = bid - 292;
#pragma unroll
        for (int p = 0; p < 16; ++p) {
            int e = j * 4096 + p * 256 + t;
            int col = e & 63, k = e >> 6;
            W2g[W2SWZ(col, k)] = f2bf_fast(W2[(size_t)k * 64 + col]);
        }
    }
}

// -------------------- K1: per-head QKV projections (bf16 MFMA) -------------
// grid (128 row-tiles, H, 3 mats), block 256 (4 waves). Linear vector staging
// from pre-swizzled WtAll / pre-converted xb. V (m==2) is written TRANSPOSED
// per 64-token tile: vb[(h*NT + rt*64)*64 + d*64 + key_local] -- the C-frag's
// 4 rr values share one d and 4 consecutive keys -> u16x4 vector stores.
__global__ __launch_bounds__(256) void qkv_kernel(
    const uint16_t* __restrict__ xb, const uint16_t* __restrict__ WtAll,
    const float* __restrict__ bq, const float* __restrict__ bk,
    const float* __restrict__ bv,
    uint16_t* __restrict__ qb, uint16_t* __restrict__ kb, uint16_t* __restrict__ vb)
{
    __shared__ uint16_t WtF[64 * 72];
    const int rt = blockIdx.x, h = blockIdx.y, m = blockIdx.z;
    const float* bias = (m == 0) ? bq : (m == 1) ? bk : bv;
    const int t = threadIdx.x, lane = t & 63, w = t >> 6;
    const int l15 = lane & 15, g = lane >> 4;

    {   // 4608 u16 = 576 u16x8, pre-swizzled in global -> linear vector copy
        const u16x8* src = (const u16x8*)(WtAll + (size_t)(m * 8 + h) * 4608);
        u16x8* dst = (u16x8*)WtF;
        dst[t] = src[t];
        dst[256 + t] = src[256 + t];
        if (t < 64) dst[512 + t] = src[512 + t];
    }
    const int row = rt * 64 + w * 16 + l15;
    bf16x8 a0 = *(const bf16x8*)&xb[(size_t)row * 64 + g * 8];
    bf16x8 a1 = *(const bf16x8*)&xb[(size_t)row * 64 + 32 + g * 8];
    __syncthreads();

    f32x4 acc[4] = {};
#pragma unroll
    for (int ct = 0; ct < 4; ++ct) {
        bf16x8 b0 = *(const bf16x8*)&WtF[SWZ(ct * 16 + l15, g * 8)];
        bf16x8 b1 = *(const bf16x8*)&WtF[SWZ(ct * 16 + l15, 32 + g * 8)];
        acc[ct] = __builtin_amdgcn_mfma_f32_16x16x32_bf16(a0, b0, acc[ct], 0, 0, 0);
        acc[ct] = __builtin_amdgcn_mfma_f32_16x16x32_bf16(a1, b1, acc[ct], 0, 0, 0);
    }
    if (m < 2) {
        uint16_t* out = (m == 0) ? qb : kb;
#pragma unroll
        for (int ct = 0; ct < 4; ++ct) {
            float bb = bias[h * 64 + ct * 16 + l15];
#pragma unroll
            for (int rr = 0; rr < 4; ++rr) {
                int orow = rt * 64 + w * 16 + g * 4 + rr;
                out[((size_t)h * NT + orow) * 64 + ct * 16 + l15] =
                    f2bf_fast(acc[ct][rr] + bb);
            }
        }
    } else {
        const size_t tb = ((size_t)h * NT + (size_t)rt * 64) * 64;
#pragma unroll
        for (int ct = 0; ct < 4; ++ct) {
            float bb = bias[h * 64 + ct * 16 + l15];
            u16x4 vo;
#pragma unroll
            for (int rr = 0; rr < 4; ++rr) vo[rr] = f2bf_fast(acc[ct][rr] + bb);
            *(u16x4*)&vb[tb + (size_t)(ct * 16 + l15) * 64 + w * 16 + g * 4] = vo;
        }
    }
}

// -------------------- K2: flash attention (swapped QK^T, V^T from global) --
// 1024 blocks x 128 threads (2 waves x 16 q-rows). V arrives tile-transposed
// so K and V staging are identical u16x8 copies -- no in-kernel transpose.
__global__ __launch_bounds__(128) void attn_kernel6(
    const uint16_t* __restrict__ qb, const uint16_t* __restrict__ kb,
    const uint16_t* __restrict__ vb, uint16_t* __restrict__ cat)
{
    __shared__ uint16_t KsF[2][64 * 72];   // K [key][d], swizzled
    __shared__ uint16_t VtF[2][64 * 72];   // V^T [d][key], swizzled
    const int bid = blockIdx.x;
    const int lbid = (bid & 7) * 128 + (bid >> 3);   // XCD swizzle, 1024%8==0
    const int pairid = lbid & 31;
    const int hb = lbid >> 5;
    const int h = hb & 7, b = hb >> 3;
    const int t = threadIdx.x, lane = t & 63, w = t >> 6;
    const int l15 = lane & 15, g = lane >> 4;
    const size_t base = ((size_t)h * NT + (size_t)b * Tt) * 64;
    const uint16_t* Qh  = qb + base;
    const uint16_t* Kh  = kb + base;
    const uint16_t* VhT = vb + base;   // + kv*4096 + d*64 + key

    for (int ph = 0; ph < 2; ++ph) {
        const int qt32 = ph ? (63 - pairid) : pairid;
        bf16x8 aq0, aq1;
        {
            int qrow = qt32 * 32 + w * 16 + l15;
            aq0 = *(const bf16x8*)&Qh[(size_t)qrow * 64 + g * 8];
            aq1 = *(const bf16x8*)&Qh[(size_t)qrow * 64 + 32 + g * 8];
        }
        f32x4 o[4] = {};
        float m_run = -INFINITY, l_run = 0.f;   // per-lane: q = l15

        __syncthreads();   // protect buf0 from previous phase
#pragma unroll
        for (int i = 0; i < 4; ++i) {
            int slot = i * 128 + t;
            int r = slot >> 3, c8 = (slot & 7) * 8;
            size_t off = (size_t)r * 64 + c8;
            u16x8 kk = *(const u16x8*)&Kh[off];
            u16x8 vv = *(const u16x8*)&VhT[off];
            *(u16x8*)&KsF[0][SWZ(r, c8)] = kk;
            *(u16x8*)&VtF[0][SWZ(r, c8)] = vv;
        }
        __syncthreads();

        const int nkv = (qt32 >> 1) + 1;
        for (int kv = 0; kv < nkv; ++kv) {
            const int cur = kv & 1;
            const bool pf = (kv + 1) < nkv;
            u16x8 pK[4], pV[4];
            if (pf) {
                const size_t poff = (size_t)(kv + 1) * 4096;
#pragma unroll
                for (int i = 0; i < 4; ++i) {
                    int slot = i * 128 + t;
                    size_t off = poff + (size_t)(slot >> 3) * 64 + (slot & 7) * 8;
                    pK[i] = *(const u16x8*)&Kh[off];
                    pV[i] = *(const u16x8*)&VhT[off];
                }
            }
            // S^T = K Q : s[kt][rj] = S[key=kt*16+g*4+rj][q=l15]
            f32x4 s[4];
#pragma unroll
            for (int kt = 0; kt < 4; ++kt) {
                bf16x8 bk0 = *(const bf16x8*)&KsF[cur][SWZ(kt * 16 + l15, g * 8)];
                bf16x8 bk1 = *(const bf16x8*)&KsF[cur][SWZ(kt * 16 + l15, 32 + g * 8)];
                f32x4 z = {};
                z = __builtin_amdgcn_mfma_f32_16x16x32_bf16(bk0, aq0, z, 0, 0, 0);
                z = __builtin_amdgcn_mfma_f32_16x16x32_bf16(bk1, aq1, z, 0, 0, 0);
                s[kt] = z;
            }
            if (kv == nkv - 1) {   // diagonal tile: mask key > q
                int qlocal = (qt32 & 1) * 32 + w * 16 + l15;
#pragma unroll
                for (int kt = 0; kt < 4; ++kt)
#pragma unroll
                    for (int rj = 0; rj < 4; ++rj)
                        if (kt * 16 + g * 4 + rj > qlocal) s[kt][rj] = -INFINITY;
            }
            float mt = s[0][0];
#pragma unroll
            for (int kt = 0; kt < 4; ++kt)
#pragma unroll
                for (int rj = 0; rj < 4; ++rj) mt = fmaxf(mt, s[kt][rj]);
            mt = fmaxf(mt, __shfl_xor(mt, 16));
            mt = fmaxf(mt, __shfl_xor(mt, 32));
            // defer-max (T13)
            if (__any((int)(mt > m_run + 8.f))) {
                float mnew = fmaxf(m_run, mt);
                float alpha = __expf(m_run - mnew);
                m_run = mnew;
                l_run *= alpha;
                float a0 = __shfl(alpha, g * 4 + 0);
                float a1 = __shfl(alpha, g * 4 + 1);
                float a2 = __shfl(alpha, g * 4 + 2);
                float a3 = __shfl(alpha, g * 4 + 3);
#pragma unroll
                for (int dt = 0; dt < 4; ++dt) {
                    o[dt][0] *= a0; o[dt][1] *= a1; o[dt][2] *= a2; o[dt][3] *= a3;
                }
            }
            float ls = 0.f;
#pragma unroll
            for (int kt = 0; kt < 4; ++kt)
#pragma unroll
                for (int rj = 0; rj < 4; ++rj) {
                    float p = __expf(s[kt][rj] - m_run);
                    s[kt][rj] = p;
                    ls += p;
                }
            ls += __shfl_xor(ls, 16);
            ls += __shfl_xor(ls, 32);
            l_run += ls;
            // pack P: lane's own values, sigma-ordered A-fragments
            union { uint32_t wd[4]; bf16x8 v; } ap0, ap1;
            ap0.wd[0] = pkbf(s[0][0], s[0][1]); ap0.wd[1] = pkbf(s[0][2], s[0][3]);
            ap0.wd[2] = pkbf(s[1][0], s[1][1]); ap0.wd[3] = pkbf(s[1][2], s[1][3]);
            ap1.wd[0] = pkbf(s[2][0], s[2][1]); ap1.wd[1] = pkbf(s[2][2], s[2][3]);
            ap1.wd[2] = pkbf(s[3][0], s[3][1]); ap1.wd[3] = pkbf(s[3][2], s[3][3]);
            // O += P V (B-frag reads sigma-permuted: two b64 per fragment)
#pragma unroll
            for (int c = 0; c < 2; ++c) {
                const bf16x8 ap = c ? ap1.v : ap0.v;
#pragma unroll
                for (int dt = 0; dt < 4; ++dt) {
                    union { u16x4 q[2]; bf16x8 v; } bb;
                    bb.q[0] = *(const u16x4*)&VtF[cur][SWZ(dt * 16 + l15, c * 32 + g * 4)];
                    bb.q[1] = *(const u16x4*)&VtF[cur][SWZ(dt * 16 + l15, c * 32 + 16 + g * 4)];
                    o[dt] = __builtin_amdgcn_mfma_f32_16x16x32_bf16(ap, bb.v, o[dt], 0, 0, 0);
                }
            }
            if (pf) {
#pragma unroll
                for (int i = 0; i < 4; ++i) {
                    int slot = i * 128 + t;
                    int r = slot >> 3, c8 = (slot & 7) * 8;
                    *(u16x8*)&KsF[cur ^ 1][SWZ(r, c8)] = pK[i];
                    *(u16x8*)&VtF[cur ^ 1][SWZ(r, c8)] = pV[i];
                }
                __syncthreads();
            }
        }
        // epilogue
        float inv = 1.f / l_run;
        float i0 = __shfl(inv, g * 4 + 0);
        float i1 = __shfl(inv, g * 4 + 1);
        float i2 = __shfl(inv, g * 4 + 2);
        float i3 = __shfl(inv, g * 4 + 3);
#pragma unroll
        for (int dt = 0; dt < 4; ++dt) {
            int rowb = qt32 * 32 + w * 16 + g * 4;
            size_t cb = ((size_t)b * Tt + rowb) * 512 + h * 64 + dt * 16 + l15;
            cat[cb]        = f2bf_fast(o[dt][0] * i0);
            cat[cb + 512]  = f2bf_fast(o[dt][1] * i1);
            cat[cb + 1024] = f2bf_fast(o[dt][2] * i2);
            cat[cb + 1536] = f2bf_fast(o[dt][3] * i3);
        }
    }
}

// -------------------- K3: fused proj+LN1+FFN+LN2 -> out --------------------
// 256 blocks x 128 threads. Weights as B-fragments straight from pre-swizzled
// global (L2-resident); no __syncthreads (wave-private LDS transposes only).
__global__ __launch_bounds__(128) void tail_kernel(
    const uint16_t* __restrict__ cat, const uint16_t* __restrict__ WptS,
    const uint16_t* __restrict__ W1g, const uint16_t* __restrict__ W2g,
    const float* __restrict__ bp, const float* __restrict__ b1,
    const float* __restrict__ b2, const float* __restrict__ x,
    const float* __restrict__ g1, const float* __restrict__ be1,
    const float* __restrict__ g2, const float* __restrict__ be2,
    float* __restrict__ out)
{
    __shared__ uint16_t h1S[2][16 * 72];
    __shared__ uint16_t hidS[2][16 * 264];
    const int rt = blockIdx.x;
    const int t = threadIdx.x, lane = t & 63, w = t >> 6;
    const int l15 = lane & 15, g = lane >> 4;
    const int arow = rt * 32 + w * 16 + l15;

    f32x4 acc[4] = {};
#pragma unroll
    for (int kt = 0; kt < 16; ++kt) {
        bf16x8 a = *(const bf16x8*)&cat[(size_t)arow * 512 + kt * 32 + g * 8];
#pragma unroll
        for (int ct = 0; ct < 4; ++ct) {
            bf16x8 bfr = *(const bf16x8*)&WptS[WPSWZ(ct * 16 + l15, kt * 32 + g * 8)];
            acc[ct] = __builtin_amdgcn_mfma_f32_16x16x32_bf16(a, bfr, acc[ct], 0, 0, 0);
        }
    }
    float bpv[4], g1v[4], b1v[4];
#pragma unroll
    for (int ct = 0; ct < 4; ++ct) {
        bpv[ct] = bp[ct * 16 + l15];
        g1v[ct] = g1[ct * 16 + l15];
        b1v[ct] = be1[ct * 16 + l15];
    }
    float hv[4][4];
#pragma unroll
    for (int rr = 0; rr < 4; ++rr) {
        int drow = rt * 32 + w * 16 + g * 4 + rr;
        float s[4], sum = 0.f;
#pragma unroll
        for (int ct = 0; ct < 4; ++ct) {
            s[ct] = acc[ct][rr] + bpv[ct] + x[(size_t)drow * 64 + ct * 16 + l15];
            sum += s[ct];
        }
        sum += __shfl_xor(sum, 1); sum += __shfl_xor(sum, 2);
        sum += __shfl_xor(sum, 4); sum += __shfl_xor(sum, 8);
        float mu = sum * (1.f / 64.f);
        float v = 0.f;
#pragma unroll
        for (int ct = 0; ct < 4; ++ct) { s[ct] -= mu; v += s[ct] * s[ct]; }
        v += __shfl_xor(v, 1); v += __shfl_xor(v, 2);
        v += __shfl_xor(v, 4); v += __shfl_xor(v, 8);
        float rstd = rsqrtf(v * (1.f / 64.f) + 1e-5f);
#pragma unroll
        for (int ct = 0; ct < 4; ++ct) {
            float h = s[ct] * rstd * g1v[ct] + b1v[ct];
            hv[ct][rr] = h;
            h1S[w][PSZ(g * 4 + rr, ct * 16 + l15)] = f2bf_fast(h);
        }
    }
    bf16x8 ha0 = *(const bf16x8*)&h1S[w][PSZ(l15, g * 8)];
    bf16x8 ha1 = *(const bf16x8*)&h1S[w][PSZ(l15, 32 + g * 8)];
#pragma unroll
    for (int nt = 0; nt < 16; ++nt) {
        f32x4 a1c = {};
        bf16x8 w10 = *(const bf16x8*)&W1g[SWZ(nt * 16 + l15, g * 8)];
        bf16x8 w11 = *(const bf16x8*)&W1g[SWZ(nt * 16 + l15, 32 + g * 8)];
        a1c = __builtin_amdgcn_mfma_f32_16x16x32_bf16(ha0, w10, a1c, 0, 0, 0);
        a1c = __builtin_amdgcn_mfma_f32_16x16x32_bf16(ha1, w11, a1c, 0, 0, 0);
        float bb1 = b1[nt * 16 + l15];
#pragma unroll
        for (int rr = 0; rr < 4; ++rr)
            hidS[w][HSZ(g * 4 + rr, nt * 16 + l15)] =
                f2bf_fast(fmaxf(a1c[rr] + bb1, 0.f));
    }
    f32x4 acc2[4] = {};
#pragma unroll
    for (int ks = 0; ks < 8; ++ks) {
        bf16x8 hfr = *(const bf16x8*)&hidS[w][HSZ(l15, ks * 32 + g * 8)];
#pragma unroll
        for (int ct = 0; ct < 4; ++ct) {
            bf16x8 w2f = *(const bf16x8*)&W2g[W2SWZ(ct * 16 + l15, ks * 32 + g * 8)];
            acc2[ct] = __builtin_amdgcn_mfma_f32_16x16x32_bf16(hfr, w2f, acc2[ct], 0, 0, 0);
        }
    }
    float b2v[4], g2v[4], be2v[4];
#pragma unroll
    for (int ct = 0; ct < 4; ++ct) {
        b2v[ct]  = b2[ct * 16 + l15];
        g2v[ct]  = g2[ct * 16 + l15];
        be2v[ct] = be2[ct * 16 + l15];
    }
#pragma unroll
    for (int rr = 0; rr < 4; ++rr) {
        int drow = rt * 32 + w * 16 + g * 4 + rr;
        float s[4], sum = 0.f;
#pragma unroll
        for (int ct = 0; ct < 4; ++ct) {
            s[ct] = acc2[ct][rr] + b2v[ct] + hv[ct][rr];
            sum += s[ct];
        }
        sum += __shfl_xor(sum, 1); sum += __shfl_xor(sum, 2);
        sum += __shfl_xor(sum, 4); sum += __shfl_xor(sum, 8);
        float mu = sum * (1.f / 64.f);
        float v = 0.f;
#pragma unroll
        for (int ct = 0; ct < 4; ++ct) { s[ct] -= mu; v += s[ct] * s[ct]; }
        v += __shfl_xor(v, 1); v += __shfl_xor(v, 2);
        v += __shfl_xor(v, 4); v += __shfl_xor(v, 8);
        float rstd = rsqrtf(v * (1.f / 64.f) + 1e-5f);
#pragma unroll
        for (int ct = 0; ct < 4; ++ct)
            out[(size_t)drow * 64 + ct * 16 + l15] =
                s[ct] * rstd * g2v[ct] + be2v[ct];
    }
}

// ---------------------------------------------------------------------------
extern "C" void kernel_launch(void* const* d_in, const int* in_sizes, int n_in,
                              void* d_out, int out_size, void* d_ws, size_t ws_size,
                              hipStream_t stream)
{
    (void)in_sizes; (void)n_in; (void)out_size; (void)ws_size;
    const float* x   = (const float*)d_in[0];
    const float* Wq  = (const float*)d_in[1];
    const float* bq  = (const float*)d_in[2];
    const float* Wk  = (const float*)d_in[3];
    const float* bk  = (const float*)d_in[4];
    const float* Wv  = (const float*)d_in[5];
    const float* bv  = (const float*)d_in[6];
    const float* Wp  = (const float*)d_in[7];
    const float* bp  = (const float*)d_in[8];
    const float* W1  = (const float*)d_in[9];
    const float* b1  = (const float*)d_in[10];
    const float* W2  = (const float*)d_in[11];
    const float* b2  = (const float*)d_in[12];
    const float* g1  = (const float*)d_in[13];
    const float* be1 = (const float*)d_in[14];
    const float* g2  = (const float*)d_in[15];
    const float* be2 = (const float*)d_in[16];
    float* outp = (float*)d_out;

    char* w = (char*)d_ws;
    uint16_t* qb   = (uint16_t*)w;                      // [H][NT][64] 8MB
    uint16_t* kb   = qb + (size_t)Hh * NT * 64;         // 8MB
    uint16_t* vb   = kb + (size_t)Hh * NT * 64;         // 8MB (tile-transposed)
    uint16_t* cat  = vb + (size_t)Hh * NT * 64;         // [NT][512] 8MB
    uint16_t* WptS = cat + (size_t)NT * 512;            // 33280 u16
    uint16_t* W1g  = WptS + 33280;                      // 18432 u16
    uint16_t* W2g  = W1g + 18432;                       // 16896 u16
    uint16_t* xb   = W2g + 16896;                       // [NT][64] 1MB
    uint16_t* WtAll= xb + (size_t)NT * 64;              // 24*4608 u16

    setup_kernel<<<dim3(296), dim3(256), 0, stream>>>(
        x, Wq, Wk, Wv, Wp, W1, W2, xb, WtAll, WptS, W1g, W2g);
    qkv_kernel<<<dim3(NT / 64, Hh, 3), dim3(256), 0, stream>>>(
        xb, WtAll, bq, bk, bv, qb, kb, vb);
    attn_kernel6<<<dim3(1024), dim3(128), 0, stream>>>(qb, kb, vb, cat);
    tail_kernel<<<dim3(256), dim3(128), 0, stream>>>(
        cat, WptS, W1g, W2g, bp, b1, b2, x, g1, be1, g2, be2, outp);
}

// Round 9
// 165.220 us; speedup vs baseline: 2.0449x; 1.0161x over previous
//
#include <hip/hip_runtime.h>
#include <hip/hip_bf16.h>
#include <stdint.h>

#define Dd 64
#define Hh 8
#define Bb 4
#define Tt 2048
#define NT (Bb * Tt)   // 8192 token rows

typedef __attribute__((ext_vector_type(4))) float f32x4;
typedef __attribute__((ext_vector_type(8))) __bf16 bf16x8;
typedef __attribute__((ext_vector_type(8))) uint16_t u16x8;
typedef __attribute__((ext_vector_type(4))) uint16_t u16x4;

__device__ __forceinline__ uint16_t f2bf_fast(float f) {
    union { __bf16 h; uint16_t u; } c; c.h = (__bf16)f; return c.u;
}
__device__ __forceinline__ uint32_t pkbf(float a, float b) {
    return (uint32_t)f2bf_fast(a) | ((uint32_t)f2bf_fast(b) << 16);
}

// XOR-swizzled layouts; same math for pre-swizzled global copies and reads.
#define SWZ(row, k)   ((row) * 72  + ((k) ^ ((((row) >> 3) & 7) << 3)))   // k<64
#define PSZ(q, k)     ((q)  * 72  + ((k) ^ ((((q)  >> 2) & 3) << 3)))    // 16 q
#define HSZ(q, k)     ((q)  * 264 + ((k) ^ ((((q)  >> 2) & 3) << 3)))    // k<256
#define W2SWZ(col, k) ((col) * 264 + ((k) ^ ((((col) >> 3) & 7) << 3)))  // k<256
#define WPSWZ(col, k) ((col) * 520 + ((k) ^ ((((col) >> 3) & 7) << 3)))  // k<512

// -------------------- K0: one-time conversions into workspace --------------
__global__ __launch_bounds__(256) void setup_kernel(
    const float* __restrict__ x,
    const float* __restrict__ Wq, const float* __restrict__ Wk,
    const float* __restrict__ Wv, const float* __restrict__ Wp,
    const float* __restrict__ W1, const float* __restrict__ W2,
    uint16_t* __restrict__ xb, uint16_t* __restrict__ WtAll,
    uint16_t* __restrict__ WptS, uint16_t* __restrict__ W1g,
    uint16_t* __restrict__ W2g)
{
    const int bid = blockIdx.x, t = threadIdx.x;
    if (bid < 256) {
        size_t base = ((size_t)bid * 256 + t) * 8;
        f32x4 a = *(const f32x4*)&x[base];
        f32x4 b = *(const f32x4*)&x[base + 4];
        u16x8 o;
#pragma unroll
        for (int j = 0; j < 4; ++j) { o[j] = f2bf_fast(a[j]); o[4 + j] = f2bf_fast(b[j]); }
        *(u16x8*)&xb[base] = o;
    } else if (bid < 280) {
        const int mh = bid - 256, m = mh / 8, h = mh % 8;
        const float* W = (m == 0) ? Wq : (m == 1) ? Wk : Wv;
        uint16_t* dst = WtAll + (size_t)mh * 4608;
#pragma unroll
        for (int p = 0; p < 4; ++p) {
            int idx = p * 256 + t;
            int k = idx >> 4, c4 = (idx & 15) * 4;
            f32x4 wv = *(const f32x4*)&W[(size_t)(h * 64 + k) * 64 + c4];
#pragma unroll
            for (int j = 0; j < 4; ++j) dst[SWZ(c4 + j, k)] = f2bf_fast(wv[j]);
        }
    } else if (bid < 288) {
        const int j = bid - 280;
#pragma unroll
        for (int p = 0; p < 16; ++p) {
            int idx = p * 256 + t;
            int col = idx & 63, k = j * 64 + (idx >> 6);
            WptS[WPSWZ(col, k)] = f2bf_fast(Wp[(size_t)k * 64 + col]);
        }
    } else if (bid < 292) {
        const int j = bid - 288;
#pragma unroll
        for (int p = 0; p < 16; ++p) {
            int e = j * 4096 + p * 256 + t;
            int col = e & 255, k = e >> 8;
            W1g[SWZ(col, k)] = f2bf_fast(W1[(size_t)k * 256 + col]);
        }
    } else {
        const int j = bid - 292;
#pragma unroll
        for (int p = 0; p < 16; ++p) {
            int e = j * 4096 + p * 256 + t;
            int col = e & 63, k = e >> 6;
            W2g[W2SWZ(col, k)] = f2bf_fast(W2[(size_t)k * 64 + col]);
        }
    }
}

// -------------------- K1: fused per-head QKV (all 3 mats per block) --------
// grid (128 row-tiles, H), block 256 (4 waves). 3 weight tiles staged once;
// x A-frags loaded once, reused for 24 MFMAs/wave. V written tile-transposed
// AND sigma-permuted in the key dim: key_store = (w>>1)*32 + g*8 + (w&1)*4+rr
// (rr in low bits -> u16x4 stays vectorized). This makes attention's PV
// B-fragment a single contiguous b128 read, bank-identical to the K reads.
__global__ __launch_bounds__(256) void qkv_kernel(
    const uint16_t* __restrict__ xb, const uint16_t* __restrict__ WtAll,
    const float* __restrict__ bq, const float* __restrict__ bk,
    const float* __restrict__ bv,
    uint16_t* __restrict__ qb, uint16_t* __restrict__ kb, uint16_t* __restrict__ vb)
{
    __shared__ uint16_t WtF[3][64 * 72];
    const int rt = blockIdx.x, h = blockIdx.y;
    const int t = threadIdx.x, lane = t & 63, w = t >> 6;
    const int l15 = lane & 15, g = lane >> 4;

#pragma unroll
    for (int m = 0; m < 3; ++m) {   // 576 u16x8 each, pre-swizzled -> linear copy
        const u16x8* src = (const u16x8*)(WtAll + (size_t)(m * 8 + h) * 4608);
        u16x8* dst = (u16x8*)WtF[m];
        dst[t] = src[t];
        dst[256 + t] = src[256 + t];
        if (t < 64) dst[512 + t] = src[512 + t];
    }
    const int row = rt * 64 + w * 16 + l15;
    bf16x8 a0 = *(const bf16x8*)&xb[(size_t)row * 64 + g * 8];
    bf16x8 a1 = *(const bf16x8*)&xb[(size_t)row * 64 + 32 + g * 8];
    __syncthreads();

#pragma unroll
    for (int m = 0; m < 3; ++m) {
        const float* bias = (m == 0) ? bq : (m == 1) ? bk : bv;
        f32x4 acc[4] = {};
#pragma unroll
        for (int ct = 0; ct < 4; ++ct) {
            bf16x8 b0 = *(const bf16x8*)&WtF[m][SWZ(ct * 16 + l15, g * 8)];
            bf16x8 b1 = *(const bf16x8*)&WtF[m][SWZ(ct * 16 + l15, 32 + g * 8)];
            acc[ct] = __builtin_amdgcn_mfma_f32_16x16x32_bf16(a0, b0, acc[ct], 0, 0, 0);
            acc[ct] = __builtin_amdgcn_mfma_f32_16x16x32_bf16(a1, b1, acc[ct], 0, 0, 0);
        }
        if (m < 2) {
            uint16_t* out = (m == 0) ? qb : kb;
#pragma unroll
            for (int ct = 0; ct < 4; ++ct) {
                float bb = bias[h * 64 + ct * 16 + l15];
#pragma unroll
                for (int rr = 0; rr < 4; ++rr) {
                    int orow = rt * 64 + w * 16 + g * 4 + rr;
                    out[((size_t)h * NT + orow) * 64 + ct * 16 + l15] =
                        f2bf_fast(acc[ct][rr] + bb);
                }
            }
        } else {
            const size_t tb = ((size_t)h * NT + (size_t)rt * 64) * 64;
            const int kcol = (w >> 1) * 32 + g * 8 + (w & 1) * 4;  // sigma-inv
#pragma unroll
            for (int ct = 0; ct < 4; ++ct) {
                float bb = bias[h * 64 + ct * 16 + l15];
                u16x4 vo;
#pragma unroll
                for (int rr = 0; rr < 4; ++rr) vo[rr] = f2bf_fast(acc[ct][rr] + bb);
                *(u16x4*)&vb[tb + (size_t)(ct * 16 + l15) * 64 + kcol] = vo;
            }
        }
    }
}

// -------------------- K2: flash attention (sigma-permuted V in memory) -----
// 1024 blocks x 128 threads. PV B-frags are contiguous b128 reads (same
// conflict-free pattern as K); P stays entirely in registers.
__global__ __launch_bounds__(128) void attn_kernel7(
    const uint16_t* __restrict__ qb, const uint16_t* __restrict__ kb,
    const uint16_t* __restrict__ vb, uint16_t* __restrict__ cat)
{
    __shared__ uint16_t KsF[2][64 * 72];   // K [key][d], swizzled
    __shared__ uint16_t VtF[2][64 * 72];   // V^T [d][key_sigma], swizzled
    const int bid = blockIdx.x;
    const int lbid = (bid & 7) * 128 + (bid >> 3);   // XCD swizzle, 1024%8==0
    const int pairid = lbid & 31;
    const int hb = lbid >> 5;
    const int h = hb & 7, b = hb >> 3;
    const int t = threadIdx.x, lane = t & 63, w = t >> 6;
    const int l15 = lane & 15, g = lane >> 4;
    const size_t base = ((size_t)h * NT + (size_t)b * Tt) * 64;
    const uint16_t* Qh  = qb + base;
    const uint16_t* Kh  = kb + base;
    const uint16_t* VhT = vb + base;   // + kv*4096 + d*64 + key_sigma

    for (int ph = 0; ph < 2; ++ph) {
        const int qt32 = ph ? (63 - pairid) : pairid;
        bf16x8 aq0, aq1;
        {
            int qrow = qt32 * 32 + w * 16 + l15;
            aq0 = *(const bf16x8*)&Qh[(size_t)qrow * 64 + g * 8];
            aq1 = *(const bf16x8*)&Qh[(size_t)qrow * 64 + 32 + g * 8];
        }
        f32x4 o[4] = {};
        float m_run = -INFINITY, l_run = 0.f;   // per-lane: q = l15

        __syncthreads();   // protect buf0 from previous phase
#pragma unroll
        for (int i = 0; i < 4; ++i) {
            int slot = i * 128 + t;
            int r = slot >> 3, c8 = (slot & 7) * 8;
            size_t off = (size_t)r * 64 + c8;
            u16x8 kk = *(const u16x8*)&Kh[off];
            u16x8 vv = *(const u16x8*)&VhT[off];
            *(u16x8*)&KsF[0][SWZ(r, c8)] = kk;
            *(u16x8*)&VtF[0][SWZ(r, c8)] = vv;
        }
        __syncthreads();

        const int nkv = (qt32 >> 1) + 1;
        for (int kv = 0; kv < nkv; ++kv) {
            const int cur = kv & 1;
            const bool pf = (kv + 1) < nkv;
            u16x8 pK[4], pV[4];
            if (pf) {
                const size_t poff = (size_t)(kv + 1) * 4096;
#pragma unroll
                for (int i = 0; i < 4; ++i) {
                    int slot = i * 128 + t;
                    size_t off = poff + (size_t)(slot >> 3) * 64 + (slot & 7) * 8;
                    pK[i] = *(const u16x8*)&Kh[off];
                    pV[i] = *(const u16x8*)&VhT[off];
                }
            }
            // S^T = K Q : s[kt][rj] = S[key=kt*16+g*4+rj][q=l15]
            f32x4 s[4];
#pragma unroll
            for (int kt = 0; kt < 4; ++kt) {
                bf16x8 bk0 = *(const bf16x8*)&KsF[cur][SWZ(kt * 16 + l15, g * 8)];
                bf16x8 bk1 = *(const bf16x8*)&KsF[cur][SWZ(kt * 16 + l15, 32 + g * 8)];
                f32x4 z = {};
                z = __builtin_amdgcn_mfma_f32_16x16x32_bf16(bk0, aq0, z, 0, 0, 0);
                z = __builtin_amdgcn_mfma_f32_16x16x32_bf16(bk1, aq1, z, 0, 0, 0);
                s[kt] = z;
            }
            if (kv == nkv - 1) {   // diagonal tile: mask key > q
                int qlocal = (qt32 & 1) * 32 + w * 16 + l15;
#pragma unroll
                for (int kt = 0; kt < 4; ++kt)
#pragma unroll
                    for (int rj = 0; rj < 4; ++rj)
                        if (kt * 16 + g * 4 + rj > qlocal) s[kt][rj] = -INFINITY;
            }
            // row max (nested triples -> v_max3)
            float mt = fmaxf(fmaxf(fmaxf(s[0][0], s[0][1]), fmaxf(s[0][2], s[0][3])),
                             fmaxf(fmaxf(s[1][0], s[1][1]), fmaxf(s[1][2], s[1][3])));
            mt = fmaxf(mt, fmaxf(fmaxf(fmaxf(s[2][0], s[2][1]), fmaxf(s[2][2], s[2][3])),
                                 fmaxf(fmaxf(s[3][0], s[3][1]), fmaxf(s[3][2], s[3][3]))));
            mt = fmaxf(mt, __shfl_xor(mt, 16));
            mt = fmaxf(mt, __shfl_xor(mt, 32));
            // defer-max (T13)
            if (__any((int)(mt > m_run + 8.f))) {
                float mnew = fmaxf(m_run, mt);
                float alpha = __expf(m_run - mnew);
                m_run = mnew;
                l_run *= alpha;
                float a0 = __shfl(alpha, g * 4 + 0);
                float a1 = __shfl(alpha, g * 4 + 1);
                float a2 = __shfl(alpha, g * 4 + 2);
                float a3 = __shfl(alpha, g * 4 + 3);
#pragma unroll
                for (int dt = 0; dt < 4; ++dt) {
                    o[dt][0] *= a0; o[dt][1] *= a1; o[dt][2] *= a2; o[dt][3] *= a3;
                }
            }
            float ls = 0.f;
#pragma unroll
            for (int kt = 0; kt < 4; ++kt)
#pragma unroll
                for (int rj = 0; rj < 4; ++rj) {
                    float p = __expf(s[kt][rj] - m_run);
                    s[kt][rj] = p;
                    ls += p;
                }
            ls += __shfl_xor(ls, 16);
            ls += __shfl_xor(ls, 32);
            l_run += ls;
            // pack P (lane-local, sigma slot order)
            union { uint32_t wd[4]; bf16x8 v; } ap0, ap1;
            ap0.wd[0] = pkbf(s[0][0], s[0][1]); ap0.wd[1] = pkbf(s[0][2], s[0][3]);
            ap0.wd[2] = pkbf(s[1][0], s[1][1]); ap0.wd[3] = pkbf(s[1][2], s[1][3]);
            ap1.wd[0] = pkbf(s[2][0], s[2][1]); ap1.wd[1] = pkbf(s[2][2], s[2][3]);
            ap1.wd[2] = pkbf(s[3][0], s[3][1]); ap1.wd[3] = pkbf(s[3][2], s[3][3]);
            // O += P V : B-frag is one contiguous b128 (conflict-free like K)
#pragma unroll
            for (int c = 0; c < 2; ++c) {
                const bf16x8 ap = c ? ap1.v : ap0.v;
#pragma unroll
                for (int dt = 0; dt < 4; ++dt) {
                    bf16x8 bv = *(const bf16x8*)&VtF[cur][SWZ(dt * 16 + l15, c * 32 + g * 8)];
                    o[dt] = __builtin_amdgcn_mfma_f32_16x16x32_bf16(ap, bv, o[dt], 0, 0, 0);
                }
            }
            if (pf) {
#pragma unroll
                for (int i = 0; i < 4; ++i) {
                    int slot = i * 128 + t;
                    int r = slot >> 3, c8 = (slot & 7) * 8;
                    *(u16x8*)&KsF[cur ^ 1][SWZ(r, c8)] = pK[i];
                    *(u16x8*)&VtF[cur ^ 1][SWZ(r, c8)] = pV[i];
                }
                __syncthreads();
            }
        }
        // epilogue
        float inv = 1.f / l_run;
        float i0 = __shfl(inv, g * 4 + 0);
        float i1 = __shfl(inv, g * 4 + 1);
        float i2 = __shfl(inv, g * 4 + 2);
        float i3 = __shfl(inv, g * 4 + 3);
#pragma unroll
        for (int dt = 0; dt < 4; ++dt) {
            int rowb = qt32 * 32 + w * 16 + g * 4;
            size_t cb = ((size_t)b * Tt + rowb) * 512 + h * 64 + dt * 16 + l15;
            cat[cb]        = f2bf_fast(o[dt][0] * i0);
            cat[cb + 512]  = f2bf_fast(o[dt][1] * i1);
            cat[cb + 1024] = f2bf_fast(o[dt][2] * i2);
            cat[cb + 1536] = f2bf_fast(o[dt][3] * i3);
        }
    }
}

// -------------------- K3: fused proj+LN1+FFN+LN2 -> out --------------------
__global__ __launch_bounds__(128) void tail_kernel(
    const uint16_t* __restrict__ cat, const uint16_t* __restrict__ WptS,
    const uint16_t* __restrict__ W1g, const uint16_t* __restrict__ W2g,
    const float* __restrict__ bp, const float* __restrict__ b1,
    const float* __restrict__ b2, const float* __restrict__ x,
    const float* __restrict__ g1, const float* __restrict__ be1,
    const float* __restrict__ g2, const float* __restrict__ be2,
    float* __restrict__ out)
{
    __shared__ uint16_t h1S[2][16 * 72];
    __shared__ uint16_t hidS[2][16 * 264];
    const int rt = blockIdx.x;
    const int t = threadIdx.x, lane = t & 63, w = t >> 6;
    const int l15 = lane & 15, g = lane >> 4;
    const int arow = rt * 32 + w * 16 + l15;

    f32x4 acc[4] = {};
#pragma unroll
    for (int kt = 0; kt < 16; ++kt) {
        bf16x8 a = *(const bf16x8*)&cat[(size_t)arow * 512 + kt * 32 + g * 8];
#pragma unroll
        for (int ct = 0; ct < 4; ++ct) {
            bf16x8 bfr = *(const bf16x8*)&WptS[WPSWZ(ct * 16 + l15, kt * 32 + g * 8)];
            acc[ct] = __builtin_amdgcn_mfma_f32_16x16x32_bf16(a, bfr, acc[ct], 0, 0, 0);
        }
    }
    float bpv[4], g1v[4], b1v[4];
#pragma unroll
    for (int ct = 0; ct < 4; ++ct) {
        bpv[ct] = bp[ct * 16 + l15];
        g1v[ct] = g1[ct * 16 + l15];
        b1v[ct] = be1[ct * 16 + l15];
    }
    float hv[4][4];
#pragma unroll
    for (int rr = 0; rr < 4; ++rr) {
        int drow = rt * 32 + w * 16 + g * 4 + rr;
        float s[4], sum = 0.f;
#pragma unroll
        for (int ct = 0; ct < 4; ++ct) {
            s[ct] = acc[ct][rr] + bpv[ct] + x[(size_t)drow * 64 + ct * 16 + l15];
            sum += s[ct];
        }
        sum += __shfl_xor(sum, 1); sum += __shfl_xor(sum, 2);
        sum += __shfl_xor(sum, 4); sum += __shfl_xor(sum, 8);
        float mu = sum * (1.f / 64.f);
        float v = 0.f;
#pragma unroll
        for (int ct = 0; ct < 4; ++ct) { s[ct] -= mu; v += s[ct] * s[ct]; }
        v += __shfl_xor(v, 1); v += __shfl_xor(v, 2);
        v += __shfl_xor(v, 4); v += __shfl_xor(v, 8);
        float rstd = rsqrtf(v * (1.f / 64.f) + 1e-5f);
#pragma unroll
        for (int ct = 0; ct < 4; ++ct) {
            float h = s[ct] * rstd * g1v[ct] + b1v[ct];
            hv[ct][rr] = h;
            h1S[w][PSZ(g * 4 + rr, ct * 16 + l15)] = f2bf_fast(h);
        }
    }
    bf16x8 ha0 = *(const bf16x8*)&h1S[w][PSZ(l15, g * 8)];
    bf16x8 ha1 = *(const bf16x8*)&h1S[w][PSZ(l15, 32 + g * 8)];
#pragma unroll
    for (int nt = 0; nt < 16; ++nt) {
        f32x4 a1c = {};
        bf16x8 w10 = *(const bf16x8*)&W1g[SWZ(nt * 16 + l15, g * 8)];
        bf16x8 w11 = *(const bf16x8*)&W1g[SWZ(nt * 16 + l15, 32 + g * 8)];
        a1c = __builtin_amdgcn_mfma_f32_16x16x32_bf16(ha0, w10, a1c, 0, 0, 0);
        a1c = __builtin_amdgcn_mfma_f32_16x16x32_bf16(ha1, w11, a1c, 0, 0, 0);
        float bb1 = b1[nt * 16 + l15];
#pragma unroll
        for (int rr = 0; rr < 4; ++rr)
            hidS[w][HSZ(g * 4 + rr, nt * 16 + l15)] =
                f2bf_fast(fmaxf(a1c[rr] + bb1, 0.f));
    }
    f32x4 acc2[4] = {};
#pragma unroll
    for (int ks = 0; ks < 8; ++ks) {
        bf16x8 hfr = *(const bf16x8*)&hidS[w][HSZ(l15, ks * 32 + g * 8)];
#pragma unroll
        for (int ct = 0; ct < 4; ++ct) {
            bf16x8 w2f = *(const bf16x8*)&W2g[W2SWZ(ct * 16 + l15, ks * 32 + g * 8)];
            acc2[ct] = __builtin_amdgcn_mfma_f32_16x16x32_bf16(hfr, w2f, acc2[ct], 0, 0, 0);
        }
    }
    float b2v[4], g2v[4], be2v[4];
#pragma unroll
    for (int ct = 0; ct < 4; ++ct) {
        b2v[ct]  = b2[ct * 16 + l15];
        g2v[ct]  = g2[ct * 16 + l15];
        be2v[ct] = be2[ct * 16 + l15];
    }
#pragma unroll
    for (int rr = 0; rr < 4; ++rr) {
        int drow = rt * 32 + w * 16 + g * 4 + rr;
        float s[4], sum = 0.f;
#pragma unroll
        for (int ct = 0; ct < 4; ++ct) {
            s[ct] = acc2[ct][rr] + b2v[ct] + hv[ct][rr];
            sum += s[ct];
        }
        sum += __shfl_xor(sum, 1); sum += __shfl_xor(sum, 2);
        sum += __shfl_xor(sum, 4); sum += __shfl_xor(sum, 8);
        float mu = sum * (1.f / 64.f);
        float v = 0.f;
#pragma unroll
        for (int ct = 0; ct < 4; ++ct) { s[ct] -= mu; v += s[ct] * s[ct]; }
        v += __shfl_xor(v, 1); v += __shfl_xor(v, 2);
        v += __shfl_xor(v, 4); v += __shfl_xor(v, 8);
        float rstd = rsqrtf(v * (1.f / 64.f) + 1e-5f);
#pragma unroll
        for (int ct = 0; ct < 4; ++ct)
            out[(size_t)drow * 64 + ct * 16 + l15] =
                s[ct] * rstd * g2v[ct] + be2v[ct];
    }
}

// ---------------------------------------------------------------------------
extern "C" void kernel_launch(void* const* d_in, const int* in_sizes, int n_in,
                              void* d_out, int out_size, void* d_ws, size_t ws_size,
                              hipStream_t stream)
{
    (void)in_sizes; (void)n_in; (void)out_size; (void)ws_size;
    const float* x   = (const float*)d_in[0];
    const float* Wq  = (const float*)d_in[1];
    const float* bq  = (const float*)d_in[2];
    const float* Wk  = (const float*)d_in[3];
    const float* bk  = (const float*)d_in[4];
    const float* Wv  = (const float*)d_in[5];
    const float* bv  = (const float*)d_in[6];
    const float* Wp  = (const float*)d_in[7];
    const float* bp  = (const float*)d_in[8];
    const float* W1  = (const float*)d_in[9];
    const float* b1  = (const float*)d_in[10];
    const float* W2  = (const float*)d_in[11];
    const float* b2  = (const float*)d_in[12];
    const float* g1  = (const float*)d_in[13];
    const float* be1 = (const float*)d_in[14];
    const float* g2  = (const float*)d_in[15];
    const float* be2 = (const float*)d_in[16];
    float* outp = (float*)d_out;

    char* w = (char*)d_ws;
    uint16_t* qb   = (uint16_t*)w;                      // [H][NT][64] 8MB
    uint16_t* kb   = qb + (size_t)Hh * NT * 64;         // 8MB
    uint16_t* vb   = kb + (size_t)Hh * NT * 64;         // 8MB (tile-T, sigma)
    uint16_t* cat  = vb + (size_t)Hh * NT * 64;         // [NT][512] 8MB
    uint16_t* WptS = cat + (size_t)NT * 512;            // 33280 u16
    uint16_t* W1g  = WptS + 33280;                      // 18432 u16
    uint16_t* W2g  = W1g + 18432;                       // 16896 u16
    uint16_t* xb   = W2g + 16896;                       // [NT][64] 1MB
    uint16_t* WtAll= xb + (size_t)NT * 64;              // 24*4608 u16

    setup_kernel<<<dim3(296), dim3(256), 0, stream>>>(
        x, Wq, Wk, Wv, Wp, W1, W2, xb, WtAll, WptS, W1g, W2g);
    qkv_kernel<<<dim3(NT / 64, Hh), dim3(256), 0, stream>>>(
        xb, WtAll, bq, bk, bv, qb, kb, vb);
    attn_kernel7<<<dim3(1024), dim3(128), 0, stream>>>(qb, kb, vb, cat);
    tail_kernel<<<dim3(256), dim3(128), 0, stream>>>(
        cat, WptS, W1g, W2g, bp, b1, b2, x, g1, be1, g2, be2, outp);
}

// Round 10
// 162.620 us; speedup vs baseline: 2.0776x; 1.0160x over previous
//
#include <hip/hip_runtime.h>
#include <hip/hip_bf16.h>
#include <stdint.h>

#define Dd 64
#define Hh 8
#define Bb 4
#define Tt 2048
#define NT (Bb * Tt)   // 8192 token rows

typedef __attribute__((ext_vector_type(4))) float f32x4;
typedef __attribute__((ext_vector_type(8))) __bf16 bf16x8;
typedef __attribute__((ext_vector_type(8))) uint16_t u16x8;
typedef __attribute__((ext_vector_type(4))) uint16_t u16x4;

__device__ __forceinline__ uint16_t f2bf_fast(float f) {
    union { __bf16 h; uint16_t u; } c; c.h = (__bf16)f; return c.u;
}
__device__ __forceinline__ uint32_t pkbf(float a, float b) {
    return (uint32_t)f2bf_fast(a) | ((uint32_t)f2bf_fast(b) << 16);
}

// XOR-swizzled layouts; same math for pre-swizzled global copies and reads.
#define SWZ(row, k)   ((row) * 72  + ((k) ^ ((((row) >> 3) & 7) << 3)))   // k<64
#define PSZ(q, k)     ((q)  * 72  + ((k) ^ ((((q)  >> 2) & 3) << 3)))    // 16 q
#define HSZ(q, k)     ((q)  * 264 + ((k) ^ ((((q)  >> 2) & 3) << 3)))    // k<256
#define W2SWZ(col, k) ((col) * 264 + ((k) ^ ((((col) >> 3) & 7) << 3)))  // k<256
#define WPSWZ(col, k) ((col) * 520 + ((k) ^ ((((col) >> 3) & 7) << 3)))  // k<512

#define LOG2E 1.44269504f

// -------------------- K0: one-time conversions into workspace --------------
__global__ __launch_bounds__(256) void setup_kernel(
    const float* __restrict__ x,
    const float* __restrict__ Wq, const float* __restrict__ Wk,
    const float* __restrict__ Wv, const float* __restrict__ Wp,
    const float* __restrict__ W1, const float* __restrict__ W2,
    uint16_t* __restrict__ xb, uint16_t* __restrict__ WtAll,
    uint16_t* __restrict__ WptS, uint16_t* __restrict__ W1g,
    uint16_t* __restrict__ W2g)
{
    const int bid = blockIdx.x, t = threadIdx.x;
    if (bid < 256) {
        size_t base = ((size_t)bid * 256 + t) * 8;
        f32x4 a = *(const f32x4*)&x[base];
        f32x4 b = *(const f32x4*)&x[base + 4];
        u16x8 o;
#pragma unroll
        for (int j = 0; j < 4; ++j) { o[j] = f2bf_fast(a[j]); o[4 + j] = f2bf_fast(b[j]); }
        *(u16x8*)&xb[base] = o;
    } else if (bid < 280) {
        const int mh = bid - 256, m = mh / 8, h = mh % 8;
        const float* W = (m == 0) ? Wq : (m == 1) ? Wk : Wv;
        uint16_t* dst = WtAll + (size_t)mh * 4608;
#pragma unroll
        for (int p = 0; p < 4; ++p) {
            int idx = p * 256 + t;
            int k = idx >> 4, c4 = (idx & 15) * 4;
            f32x4 wv = *(const f32x4*)&W[(size_t)(h * 64 + k) * 64 + c4];
#pragma unroll
            for (int j = 0; j < 4; ++j) dst[SWZ(c4 + j, k)] = f2bf_fast(wv[j]);
        }
    } else if (bid < 288) {
        const int j = bid - 280;
#pragma unroll
        for (int p = 0; p < 16; ++p) {
            int idx = p * 256 + t;
            int col = idx & 63, k = j * 64 + (idx >> 6);
            WptS[WPSWZ(col, k)] = f2bf_fast(Wp[(size_t)k * 64 + col]);
        }
    } else if (bid < 292) {
        const int j = bid - 288;
#pragma unroll
        for (int p = 0; p < 16; ++p) {
            int e = j * 4096 + p * 256 + t;
            int col = e & 255, k = e >> 8;
            W1g[SWZ(col, k)] = f2bf_fast(W1[(size_t)k * 256 + col]);
        }
    } else {
        const int j = bid - 292;
#pragma unroll
        for (int p = 0; p < 16; ++p) {
            int e = j * 4096 + p * 256 + t;
            int col = e & 63, k = e >> 6;
            W2g[W2SWZ(col, k)] = f2bf_fast(W2[(size_t)k * 64 + col]);
        }
    }
}

// -------------------- K1: fused per-head QKV (all 3 mats per block) --------
// Q output is pre-scaled by log2(e) so attention's scores arrive in the
// exp2 domain (bare v_exp_f32, no per-element multiply). V written
// tile-transposed + sigma-permuted (key_store = (w>>1)*32+g*8+(w&1)*4+rr).
__global__ __launch_bounds__(256) void qkv_kernel(
    const uint16_t* __restrict__ xb, const uint16_t* __restrict__ WtAll,
    const float* __restrict__ bq, const float* __restrict__ bk,
    const float* __restrict__ bv,
    uint16_t* __restrict__ qb, uint16_t* __restrict__ kb, uint16_t* __restrict__ vb)
{
    __shared__ uint16_t WtF[3][64 * 72];
    const int rt = blockIdx.x, h = blockIdx.y;
    const int t = threadIdx.x, lane = t & 63, w = t >> 6;
    const int l15 = lane & 15, g = lane >> 4;

#pragma unroll
    for (int m = 0; m < 3; ++m) {
        const u16x8* src = (const u16x8*)(WtAll + (size_t)(m * 8 + h) * 4608);
        u16x8* dst = (u16x8*)WtF[m];
        dst[t] = src[t];
        dst[256 + t] = src[256 + t];
        if (t < 64) dst[512 + t] = src[512 + t];
    }
    const int row = rt * 64 + w * 16 + l15;
    bf16x8 a0 = *(const bf16x8*)&xb[(size_t)row * 64 + g * 8];
    bf16x8 a1 = *(const bf16x8*)&xb[(size_t)row * 64 + 32 + g * 8];
    __syncthreads();

#pragma unroll
    for (int m = 0; m < 3; ++m) {
        const float* bias = (m == 0) ? bq : (m == 1) ? bk : bv;
        f32x4 acc[4] = {};
#pragma unroll
        for (int ct = 0; ct < 4; ++ct) {
            bf16x8 b0 = *(const bf16x8*)&WtF[m][SWZ(ct * 16 + l15, g * 8)];
            bf16x8 b1 = *(const bf16x8*)&WtF[m][SWZ(ct * 16 + l15, 32 + g * 8)];
            acc[ct] = __builtin_amdgcn_mfma_f32_16x16x32_bf16(a0, b0, acc[ct], 0, 0, 0);
            acc[ct] = __builtin_amdgcn_mfma_f32_16x16x32_bf16(a1, b1, acc[ct], 0, 0, 0);
        }
        if (m < 2) {
            uint16_t* out = (m == 0) ? qb : kb;
            const float scl = (m == 0) ? LOG2E : 1.0f;
#pragma unroll
            for (int ct = 0; ct < 4; ++ct) {
                float bb = bias[h * 64 + ct * 16 + l15];
#pragma unroll
                for (int rr = 0; rr < 4; ++rr) {
                    int orow = rt * 64 + w * 16 + g * 4 + rr;
                    out[((size_t)h * NT + orow) * 64 + ct * 16 + l15] =
                        f2bf_fast((acc[ct][rr] + bb) * scl);
                }
            }
        } else {
            const size_t tb = ((size_t)h * NT + (size_t)rt * 64) * 64;
            const int kcol = (w >> 1) * 32 + g * 8 + (w & 1) * 4;  // sigma-inv
#pragma unroll
            for (int ct = 0; ct < 4; ++ct) {
                float bb = bias[h * 64 + ct * 16 + l15];
                u16x4 vo;
#pragma unroll
                for (int rr = 0; rr < 4; ++rr) vo[rr] = f2bf_fast(acc[ct][rr] + bb);
                *(u16x4*)&vb[tb + (size_t)(ct * 16 + l15) * 64 + kcol] = vo;
            }
        }
    }
}

// -------------------- K2: flash attention (4 waves, 64-row q-tiles) --------
// 512 blocks x 256 threads; block handles q-tiles {p, 31-p} (33 kv-iters).
// One K/V staging serves 64 q-rows (staging per thread halved vs r9).
// Row-sum l computed by mfma(P, ones) -> lands in O's C-layout: no ls adds,
// no ls shuffles, no epilogue inv broadcast. Scores arrive in exp2 domain.
__global__ __launch_bounds__(256) void attn_kernel8(
    const uint16_t* __restrict__ qb, const uint16_t* __restrict__ kb,
    const uint16_t* __restrict__ vb, uint16_t* __restrict__ cat)
{
    __shared__ uint16_t KsF[2][64 * 72];   // K [key][d], swizzled
    __shared__ uint16_t VtF[2][64 * 72];   // V^T [d][key_sigma], swizzled
    const int bid = blockIdx.x;
    const int lbid = (bid & 7) * 64 + (bid >> 3);   // XCD swizzle, 512%8==0
    const int pairid = lbid & 15;
    const int hb = lbid >> 4;
    const int h = hb & 7, b = hb >> 3;
    const int t = threadIdx.x, lane = t & 63, w = t >> 6;   // w in 0..3
    const int l15 = lane & 15, g = lane >> 4;
    const size_t base = ((size_t)h * NT + (size_t)b * Tt) * 64;
    const uint16_t* Qh  = qb + base;
    const uint16_t* Kh  = kb + base;
    const uint16_t* VhT = vb + base;   // + kv*4096 + d*64 + key_sigma

    union { uint32_t u[4]; bf16x8 v; } onesu;
#pragma unroll
    for (int j = 0; j < 4; ++j) onesu.u[j] = 0x3F803F80u;   // bf16 1.0 x2
    const bf16x8 ones = onesu.v;

    for (int ph = 0; ph < 2; ++ph) {
        const int qt = ph ? (31 - pairid) : pairid;
        bf16x8 aq0, aq1;
        {
            int qrow = qt * 64 + w * 16 + l15;
            aq0 = *(const bf16x8*)&Qh[(size_t)qrow * 64 + g * 8];
            aq1 = *(const bf16x8*)&Qh[(size_t)qrow * 64 + 32 + g * 8];
        }
        f32x4 o[4] = {};                // O[q=g*4+rj][d=dt*16+l15]
        f32x4 l_acc = {};               // l[q=g*4+rj] (all l15 identical)
        float m_run = -INFINITY;        // per-lane: q = l15 (log2 domain)

        __syncthreads();   // protect buf0 from previous phase
#pragma unroll
        for (int i = 0; i < 2; ++i) {
            int slot = i * 256 + t;
            int r = slot >> 3, c8 = (slot & 7) * 8;
            size_t off = (size_t)r * 64 + c8;
            u16x8 kk = *(const u16x8*)&Kh[off];
            u16x8 vv = *(const u16x8*)&VhT[off];
            *(u16x8*)&KsF[0][SWZ(r, c8)] = kk;
            *(u16x8*)&VtF[0][SWZ(r, c8)] = vv;
        }
        __syncthreads();

        const int nkv = qt + 1;
        for (int kv = 0; kv < nkv; ++kv) {
            const int cur = kv & 1;
            const bool pf = (kv + 1) < nkv;
            u16x8 pK[2], pV[2];
            if (pf) {
                const size_t poff = (size_t)(kv + 1) * 4096;
#pragma unroll
                for (int i = 0; i < 2; ++i) {
                    int slot = i * 256 + t;
                    size_t off = poff + (size_t)(slot >> 3) * 64 + (slot & 7) * 8;
                    pK[i] = *(const u16x8*)&Kh[off];
                    pV[i] = *(const u16x8*)&VhT[off];
                }
            }
            // S^T = K Q : s[kt][rj] = S[key=kt*16+g*4+rj][q=l15] (log2 dom.)
            f32x4 s[4];
#pragma unroll
            for (int kt = 0; kt < 4; ++kt) {
                bf16x8 bk0 = *(const bf16x8*)&KsF[cur][SWZ(kt * 16 + l15, g * 8)];
                bf16x8 bk1 = *(const bf16x8*)&KsF[cur][SWZ(kt * 16 + l15, 32 + g * 8)];
                f32x4 z = {};
                z = __builtin_amdgcn_mfma_f32_16x16x32_bf16(bk0, aq0, z, 0, 0, 0);
                z = __builtin_amdgcn_mfma_f32_16x16x32_bf16(bk1, aq1, z, 0, 0, 0);
                s[kt] = z;
            }
            if (kv == nkv - 1) {   // diagonal tile: mask key > q (tile-local)
                int qlocal = w * 16 + l15;
#pragma unroll
                for (int kt = 0; kt < 4; ++kt)
#pragma unroll
                    for (int rj = 0; rj < 4; ++rj)
                        if (kt * 16 + g * 4 + rj > qlocal) s[kt][rj] = -INFINITY;
            }
            // row max (v_max3-friendly chains)
            float mt = fmaxf(fmaxf(fmaxf(s[0][0], s[0][1]), fmaxf(s[0][2], s[0][3])),
                             fmaxf(fmaxf(s[1][0], s[1][1]), fmaxf(s[1][2], s[1][3])));
            mt = fmaxf(mt, fmaxf(fmaxf(fmaxf(s[2][0], s[2][1]), fmaxf(s[2][2], s[2][3])),
                                 fmaxf(fmaxf(s[3][0], s[3][1]), fmaxf(s[3][2], s[3][3]))));
            mt = fmaxf(mt, __shfl_xor(mt, 16));
            mt = fmaxf(mt, __shfl_xor(mt, 32));
            // defer-max (T13), threshold 8*log2e in exp2 domain
            if (__any((int)(mt > m_run + 11.5409f))) {
                float mnew = fmaxf(m_run, mt);
                float alpha = exp2f(m_run - mnew);
                m_run = mnew;
                float a0 = __shfl(alpha, g * 4 + 0);
                float a1 = __shfl(alpha, g * 4 + 1);
                float a2 = __shfl(alpha, g * 4 + 2);
                float a3 = __shfl(alpha, g * 4 + 3);
                l_acc[0] *= a0; l_acc[1] *= a1; l_acc[2] *= a2; l_acc[3] *= a3;
#pragma unroll
                for (int dt = 0; dt < 4; ++dt) {
                    o[dt][0] *= a0; o[dt][1] *= a1; o[dt][2] *= a2; o[dt][3] *= a3;
                }
            }
            // P = 2^(s - m) ; no VALU row-sum (MFMA ones-column below)
#pragma unroll
            for (int kt = 0; kt < 4; ++kt)
#pragma unroll
                for (int rj = 0; rj < 4; ++rj)
                    s[kt][rj] = exp2f(s[kt][rj] - m_run);
            // pack P (lane-local, sigma slot order)
            union { uint32_t wd[4]; bf16x8 v; } ap0, ap1;
            ap0.wd[0] = pkbf(s[0][0], s[0][1]); ap0.wd[1] = pkbf(s[0][2], s[0][3]);
            ap0.wd[2] = pkbf(s[1][0], s[1][1]); ap0.wd[3] = pkbf(s[1][2], s[1][3]);
            ap1.wd[0] = pkbf(s[2][0], s[2][1]); ap1.wd[1] = pkbf(s[2][2], s[2][3]);
            ap1.wd[2] = pkbf(s[3][0], s[3][1]); ap1.wd[3] = pkbf(s[3][2], s[3][3]);
            // O += P V ; l += P ones  (l in same C-layout as O)
#pragma unroll
            for (int c = 0; c < 2; ++c) {
                const bf16x8 ap = c ? ap1.v : ap0.v;
                l_acc = __builtin_amdgcn_mfma_f32_16x16x32_bf16(ap, ones, l_acc, 0, 0, 0);
#pragma unroll
                for (int dt = 0; dt < 4; ++dt) {
                    bf16x8 bv = *(const bf16x8*)&VtF[cur][SWZ(dt * 16 + l15, c * 32 + g * 8)];
                    o[dt] = __builtin_amdgcn_mfma_f32_16x16x32_bf16(ap, bv, o[dt], 0, 0, 0);
                }
            }
            if (pf) {
#pragma unroll
                for (int i = 0; i < 2; ++i) {
                    int slot = i * 256 + t;
                    int r = slot >> 3, c8 = (slot & 7) * 8;
                    *(u16x8*)&KsF[cur ^ 1][SWZ(r, c8)] = pK[i];
                    *(u16x8*)&VtF[cur ^ 1][SWZ(r, c8)] = pV[i];
                }
                __syncthreads();
            }
        }
        // epilogue: inv already in O's layout -- no shuffles
        f32x4 inv;
#pragma unroll
        for (int rj = 0; rj < 4; ++rj) inv[rj] = 1.f / l_acc[rj];
#pragma unroll
        for (int dt = 0; dt < 4; ++dt) {
            int rowb = qt * 64 + w * 16 + g * 4;
            size_t cb = ((size_t)b * Tt + rowb) * 512 + h * 64 + dt * 16 + l15;
            cat[cb]        = f2bf_fast(o[dt][0] * inv[0]);
            cat[cb + 512]  = f2bf_fast(o[dt][1] * inv[1]);
            cat[cb + 1024] = f2bf_fast(o[dt][2] * inv[2]);
            cat[cb + 1536] = f2bf_fast(o[dt][3] * inv[3]);
        }
    }
}

// -------------------- K3: fused proj+LN1+FFN+LN2 -> out --------------------
__global__ __launch_bounds__(128) void tail_kernel(
    const uint16_t* __restrict__ cat, const uint16_t* __restrict__ WptS,
    const uint16_t* __restrict__ W1g, const uint16_t* __restrict__ W2g,
    const float* __restrict__ bp, const float* __restrict__ b1,
    const float* __restrict__ b2, const float* __restrict__ x,
    const float* __restrict__ g1, const float* __restrict__ be1,
    const float* __restrict__ g2, const float* __restrict__ be2,
    float* __restrict__ out)
{
    __shared__ uint16_t h1S[2][16 * 72];
    __shared__ uint16_t hidS[2][16 * 264];
    const int rt = blockIdx.x;
    const int t = threadIdx.x, lane = t & 63, w = t >> 6;
    const int l15 = lane & 15, g = lane >> 4;
    const int arow = rt * 32 + w * 16 + l15;

    f32x4 acc[4] = {};
#pragma unroll
    for (int kt = 0; kt < 16; ++kt) {
        bf16x8 a = *(const bf16x8*)&cat[(size_t)arow * 512 + kt * 32 + g * 8];
#pragma unroll
        for (int ct = 0; ct < 4; ++ct) {
            bf16x8 bfr = *(const bf16x8*)&WptS[WPSWZ(ct * 16 + l15, kt * 32 + g * 8)];
            acc[ct] = __builtin_amdgcn_mfma_f32_16x16x32_bf16(a, bfr, acc[ct], 0, 0, 0);
        }
    }
    float bpv[4], g1v[4], b1v[4];
#pragma unroll
    for (int ct = 0; ct < 4; ++ct) {
        bpv[ct] = bp[ct * 16 + l15];
        g1v[ct] = g1[ct * 16 + l15];
        b1v[ct] = be1[ct * 16 + l15];
    }
    float hv[4][4];
#pragma unroll
    for (int rr = 0; rr < 4; ++rr) {
        int drow = rt * 32 + w * 16 + g * 4 + rr;
        float s[4], sum = 0.f;
#pragma unroll
        for (int ct = 0; ct < 4; ++ct) {
            s[ct] = acc[ct][rr] + bpv[ct] + x[(size_t)drow * 64 + ct * 16 + l15];
            sum += s[ct];
        }
        sum += __shfl_xor(sum, 1); sum += __shfl_xor(sum, 2);
        sum += __shfl_xor(sum, 4); sum += __shfl_xor(sum, 8);
        float mu = sum * (1.f / 64.f);
        float v = 0.f;
#pragma unroll
        for (int ct = 0; ct < 4; ++ct) { s[ct] -= mu; v += s[ct] * s[ct]; }
        v += __shfl_xor(v, 1); v += __shfl_xor(v, 2);
        v += __shfl_xor(v, 4); v += __shfl_xor(v, 8);
        float rstd = rsqrtf(v * (1.f / 64.f) + 1e-5f);
#pragma unroll
        for (int ct = 0; ct < 4; ++ct) {
            float h = s[ct] * rstd * g1v[ct] + b1v[ct];
            hv[ct][rr] = h;
            h1S[w][PSZ(g * 4 + rr, ct * 16 + l15)] = f2bf_fast(h);
        }
    }
    bf16x8 ha0 = *(const bf16x8*)&h1S[w][PSZ(l15, g * 8)];
    bf16x8 ha1 = *(const bf16x8*)&h1S[w][PSZ(l15, 32 + g * 8)];
#pragma unroll
    for (int nt = 0; nt < 16; ++nt) {
        f32x4 a1c = {};
        bf16x8 w10 = *(const bf16x8*)&W1g[SWZ(nt * 16 + l15, g * 8)];
        bf16x8 w11 = *(const bf16x8*)&W1g[SWZ(nt * 16 + l15, 32 + g * 8)];
        a1c = __builtin_amdgcn_mfma_f32_16x16x32_bf16(ha0, w10, a1c, 0, 0, 0);
        a1c = __builtin_amdgcn_mfma_f32_16x16x32_bf16(ha1, w11, a1c, 0, 0, 0);
        float bb1 = b1[nt * 16 + l15];
#pragma unroll
        for (int rr = 0; rr < 4; ++rr)
            hidS[w][HSZ(g * 4 + rr, nt * 16 + l15)] =
                f2bf_fast(fmaxf(a1c[rr] + bb1, 0.f));
    }
    f32x4 acc2[4] = {};
#pragma unroll
    for (int ks = 0; ks < 8; ++ks) {
        bf16x8 hfr = *(const bf16x8*)&hidS[w][HSZ(l15, ks * 32 + g * 8)];
#pragma unroll
        for (int ct = 0; ct < 4; ++ct) {
            bf16x8 w2f = *(const bf16x8*)&W2g[W2SWZ(ct * 16 + l15, ks * 32 + g * 8)];
            acc2[ct] = __builtin_amdgcn_mfma_f32_16x16x32_bf16(hfr, w2f, acc2[ct], 0, 0, 0);
        }
    }
    float b2v[4], g2v[4], be2v[4];
#pragma unroll
    for (int ct = 0; ct < 4; ++ct) {
        b2v[ct]  = b2[ct * 16 + l15];
        g2v[ct]  = g2[ct * 16 + l15];
        be2v[ct] = be2[ct * 16 + l15];
    }
#pragma unroll
    for (int rr = 0; rr < 4; ++rr) {
        int drow = rt * 32 + w * 16 + g * 4 + rr;
        float s[4], sum = 0.f;
#pragma unroll
        for (int ct = 0; ct < 4; ++ct) {
            s[ct] = acc2[ct][rr] + b2v[ct] + hv[ct][rr];
            sum += s[ct];
        }
        sum += __shfl_xor(sum, 1); sum += __shfl_xor(sum, 2);
        sum += __shfl_xor(sum, 4); sum += __shfl_xor(sum, 8);
        float mu = sum * (1.f / 64.f);
        float v = 0.f;
#pragma unroll
        for (int ct = 0; ct < 4; ++ct) { s[ct] -= mu; v += s[ct] * s[ct]; }
        v += __shfl_xor(v, 1); v += __shfl_xor(v, 2);
        v += __shfl_xor(v, 4); v += __shfl_xor(v, 8);
        float rstd = rsqrtf(v * (1.f / 64.f) + 1e-5f);
#pragma unroll
        for (int ct = 0; ct < 4; ++ct)
            out[(size_t)drow * 64 + ct * 16 + l15] =
                s[ct] * rstd * g2v[ct] + be2v[ct];
    }
}

// ---------------------------------------------------------------------------
extern "C" void kernel_launch(void* const* d_in, const int* in_sizes, int n_in,
                              void* d_out, int out_size, void* d_ws, size_t ws_size,
                              hipStream_t stream)
{
    (void)in_sizes; (void)n_in; (void)out_size; (void)ws_size;
    const float* x   = (const float*)d_in[0];
    const float* Wq  = (const float*)d_in[1];
    const float* bq  = (const float*)d_in[2];
    const float* Wk  = (const float*)d_in[3];
    const float* bk  = (const float*)d_in[4];
    const float* Wv  = (const float*)d_in[5];
    const float* bv  = (const float*)d_in[6];
    const float* Wp  = (const float*)d_in[7];
    const float* bp  = (const float*)d_in[8];
    const float* W1  = (const float*)d_in[9];
    const float* b1  = (const float*)d_in[10];
    const float* W2  = (const float*)d_in[11];
    const float* b2  = (const float*)d_in[12];
    const float* g1  = (const float*)d_in[13];
    const float* be1 = (const float*)d_in[14];
    const float* g2  = (const float*)d_in[15];
    const float* be2 = (const float*)d_in[16];
    float* outp = (float*)d_out;

    char* w = (char*)d_ws;
    uint16_t* qb   = (uint16_t*)w;                      // [H][NT][64] 8MB
    uint16_t* kb   = qb + (size_t)Hh * NT * 64;         // 8MB
    uint16_t* vb   = kb + (size_t)Hh * NT * 64;         // 8MB (tile-T, sigma)
    uint16_t* cat  = vb + (size_t)Hh * NT * 64;         // [NT][512] 8MB
    uint16_t* WptS = cat + (size_t)NT * 512;            // 33280 u16
    uint16_t* W1g  = WptS + 33280;                      // 18432 u16
    uint16_t* W2g  = W1g + 18432;                       // 16896 u16
    uint16_t* xb   = W2g + 16896;                       // [NT][64] 1MB
    uint16_t* WtAll= xb + (size_t)NT * 64;              // 24*4608 u16

    setup_kernel<<<dim3(296), dim3(256), 0, stream>>>(
        x, Wq, Wk, Wv, Wp, W1, W2, xb, WtAll, WptS, W1g, W2g);
    qkv_kernel<<<dim3(NT / 64, Hh), dim3(256), 0, stream>>>(
        xb, WtAll, bq, bk, bv, qb, kb, vb);
    attn_kernel8<<<dim3(512), dim3(256), 0, stream>>>(qb, kb, vb, cat);
    tail_kernel<<<dim3(256), dim3(128), 0, stream>>>(
        cat, WptS, W1g, W2g, bp, b1, b2, x, g1, be1, g2, be2, outp);
}